// Round 5
// baseline (13881.560 us; speedup 1.0000x reference)
//
#include <hip/hip_runtime.h>
#include <hip/hip_bf16.h>

#define UNITS 1024
#define FEAT  16
#define TSTEPS 512
#define OUTSTEPS 24
#define BATCH 256
#define KTOT  1088   // 16 (x) + 1024 (h) + 48 pad
#define KP    1096   // padded LDS stride (2192B), conflict-reduced b128
#define NROWS 4096   // 4*UNITS, reordered r = 4*u + gate

// LDS: Ws [64][KP] bf16 (140288) + red 16KB + hstage 64 rows x 40B (2560)
#define RED_OFF    (64 * KP * 2)
#define HST_OFF    (RED_OFF + 16384)
#define SMEM_BYTES (HST_OFF + 2560)   // 159,232 <= 160 KiB

#define NGBAR   96
#define CTR_TOT ((TSTEPS * 4 + NGBAR) * 16)

typedef __bf16 bf16x8 __attribute__((ext_vector_type(8)));
typedef float  f32x4  __attribute__((ext_vector_type(4)));

__device__ __forceinline__ float sigmoidf_(float x) { return 1.f / (1.f + __expf(-x)); }
__device__ __forceinline__ float tanhf_(float x)    { return 1.f - 2.f / (__expf(2.f * x) + 1.f); }

// ---------------------------------------------------------------------------
// Build Wcat_T[r][k] (bf16, row-major, stride KTOT), r = 4*u + g.
// ---------------------------------------------------------------------------
__global__ __launch_bounds__(256) void prep_weights(const float* __restrict__ kern,
                                                    const float* __restrict__ rec,
                                                    __bf16* __restrict__ Wcat) {
    __shared__ __align__(16) __bf16 tile[64][72];
    int r0 = blockIdx.x * 64;
    int k0 = blockIdx.y * 64;
    int t  = threadIdx.x;
    int c_off = t & 63;
    int k_grp = t >> 6;
    int g = c_off >> 4, ui = c_off & 15;
    int u0 = r0 >> 2;
    int c  = g * 1024 + u0 + ui;
    int rl = 4 * ui + g;
    for (int i = 0; i < 16; i++) {
        int k = k0 + k_grp * 16 + i;
        float v = 0.f;
        if (k < 16)        v = kern[(size_t)k * NROWS + c];
        else if (k < 1040) v = rec[(size_t)(k - 16) * NROWS + c];
        tile[rl][k_grp * 16 + i] = (__bf16)v;
    }
    __syncthreads();
    int rl2 = t >> 2, ch = t & 3;
    bf16x8* dst = (bf16x8*)(Wcat + (size_t)(r0 + rl2) * KTOT + k0 + ch * 16);
    const bf16x8* src = (const bf16x8*)&tile[rl2][ch * 16];
    dst[0] = src[0];
    dst[1] = src[1];
}

// ---------------------------------------------------------------------------
// Zero hT, zero+x-init Abuf buffers, zero barrier counters.
// ---------------------------------------------------------------------------
__global__ __launch_bounds__(256) void prep_state(const float* __restrict__ x,
                                                  __bf16* __restrict__ Ab0,
                                                  __bf16* __restrict__ Ab1,
                                                  float* __restrict__ hT,
                                                  unsigned int* __restrict__ ctr) {
    int tid = blockIdx.x * 256 + threadIdx.x;
    int np  = gridDim.x * 256;
    for (int i = tid; i < BATCH * UNITS; i += np) hT[i] = 0.f;
    const int AB = BATCH * KTOT;
    for (int i = tid; i < 2 * AB; i += np) {
        int which = (i < AB) ? 0 : 1;
        int p = i - which * AB;
        int col = p % KTOT;
        int m   = p / KTOT;
        __bf16 v = (__bf16)0.f;
        if (which == 0 && col < FEAT) v = (__bf16)x[(size_t)m * TSTEPS * FEAT + col];
        if (which == 0) Ab0[p] = v; else Ab1[p] = v;
    }
    for (int i = tid; i < CTR_TOT; i += np) ctr[i] = 0u;
}

// ---------------------------------------------------------------------------
// Precompute per-(t,m): tv, keep-flag, bf16 x table.
// ---------------------------------------------------------------------------
__global__ __launch_bounds__(256) void prep_tv(const float* __restrict__ x,
                                               float* __restrict__ tvx,
                                               unsigned char* __restrict__ kflag,
                                               __bf16* __restrict__ xbf) {
    int m = blockIdx.x;
    for (int t = threadIdx.x; t < TSTEPS; t += 256) {
        const float* row = x + ((size_t)m * TSTEPS + t) * FEAT;
        f32x4 v0 = *(const f32x4*)row;
        f32x4 v1 = *(const f32x4*)(row + 4);
        f32x4 v2 = *(const f32x4*)(row + 8);
        f32x4 v3 = *(const f32x4*)(row + 12);
        bool keep = true;
#pragma unroll
        for (int i = 0; i < 4; ++i)
            keep = keep && (v0[i] == -1.f) && (v1[i] == -1.f) &&
                   (v2[i] == -1.f) && (v3[i] == -1.f);
        tvx[(size_t)t * BATCH + m]   = v0[0];
        kflag[(size_t)t * BATCH + m] = keep ? 1 : 0;
        __bf16* xo = xbf + ((size_t)t * BATCH + m) * 16;
        bf16x8 o0, o1;
#pragma unroll
        for (int i = 0; i < 4; ++i) { o0[i] = (__bf16)v0[i]; o0[4 + i] = (__bf16)v1[i]; }
#pragma unroll
        for (int i = 0; i < 4; ++i) { o1[i] = (__bf16)v2[i]; o1[4 + i] = (__bf16)v3[i]; }
        *(bf16x8*)xo = o0;
        *(bf16x8*)(xo + 8) = o1;
    }
}

// ---------------------------------------------------------------------------
__device__ __forceinline__ void gate_update(
    float z0, float z1, float z2, float z3,
    float bi, float bf, float bg, float bo,
    float ph, float rp, float ro, float k2,
    float tv, int kf, float& h, float& c) {
    float zi = z0 + bi, zf = z1 + bf, zg = z2 + bg, zo = z3 + bo;
    float ig = sigmoidf_(zi), fg = sigmoidf_(zf), og = sigmoidf_(zo);
    float gv = tanhf_(zg);
    float nc = fg * c + ig * gv;
    float nh = og * tanhf_(nc);
    float cr = (tv - ph) * rp;
    cr = cr - floorf(cr);
    float kup = cr * k2;
    float kk = (cr < ro) ? (2.f - kup) : (0.001f * cr);
    kk = (cr < 0.5f * ro) ? kup : kk;
    float ho = kk * nh + (1.f - kk) * h;
    float co = kk * nc + (1.f - kk) * c;
    if (kf) { ho = h; co = c; }
    h = ho; c = co;
}

// ---------------------------------------------------------------------------
// Mega persistent kernel: 512 warm steps (per-group barrier) + 24 AR
// iterations (dense1 + dense tail + AR step, grid barriers). 256 blocks x
// 512 thr, 1 block/CU (LDS-forced => all co-resident).
// Coherence: all cross-block stores = sc1 write-through atomics (L2 stays
// clean); all cross-block loads = sc0 (L1-bypass, L2-hit); one
// `s_waitcnt vmcnt(0); buffer_inv sc1` per block after every barrier
// (canonical agent-acquire) refreshes L2 from MALL. No wbl2 anywhere.
// ---------------------------------------------------------------------------
#define KSTEP(BF, KT) { \
    const __bf16* ap_ = wsbase + (KT) * 32; \
    bf16x8 a0_ = *(const bf16x8*)(ap_); \
    bf16x8 a1_ = *(const bf16x8*)(ap_ + 16 * KP); \
    bf16x8 a2_ = *(const bf16x8*)(ap_ + 32 * KP); \
    bf16x8 a3_ = *(const bf16x8*)(ap_ + 48 * KP); \
    acc0 = __builtin_amdgcn_mfma_f32_16x16x32_bf16(a0_, BF, acc0, 0, 0, 0); \
    acc1 = __builtin_amdgcn_mfma_f32_16x16x32_bf16(a1_, BF, acc1, 0, 0, 0); \
    acc2 = __builtin_amdgcn_mfma_f32_16x16x32_bf16(a2_, BF, acc2, 0, 0, 0); \
    acc3 = __builtin_amdgcn_mfma_f32_16x16x32_bf16(a3_, BF, acc3, 0, 0, 0); \
}

#define BAR_SYNC(CP, COUNT) \
    __syncthreads(); \
    if (tid == 0) { \
        __hip_atomic_fetch_add((CP), 1u, __ATOMIC_RELAXED, __HIP_MEMORY_SCOPE_AGENT); \
        while (__hip_atomic_load((CP), __ATOMIC_RELAXED, __HIP_MEMORY_SCOPE_AGENT) < (COUNT)) \
            __builtin_amdgcn_s_sleep(2); \
    } \
    __syncthreads(); \
    asm volatile("s_waitcnt vmcnt(0)\n\tbuffer_inv sc1" ::: "memory");

#define STEP_CORE(BP, TVA, KFA, WARMF) { \
    bf16x8 b0, b1, b2, b3, b4, b5, b6, b7, b8, b9, b10, b11, b12, b13, b14, b15, b16; \
    float tvr; unsigned int kfr; \
    asm volatile( \
        "global_load_dwordx4 %0, %19, off sc0\n\t" \
        "global_load_dwordx4 %1, %19, off offset:64 sc0\n\t" \
        "global_load_dwordx4 %2, %19, off offset:128 sc0\n\t" \
        "global_load_dwordx4 %3, %19, off offset:192 sc0\n\t" \
        "global_load_dwordx4 %4, %19, off offset:256 sc0\n\t" \
        "global_load_dwordx4 %5, %19, off offset:320 sc0\n\t" \
        "global_load_dwordx4 %6, %19, off offset:384 sc0\n\t" \
        "global_load_dwordx4 %7, %19, off offset:448 sc0\n\t" \
        "global_load_dwordx4 %8, %19, off offset:512 sc0\n\t" \
        "global_load_dwordx4 %9, %19, off offset:576 sc0\n\t" \
        "global_load_dwordx4 %10, %19, off offset:640 sc0\n\t" \
        "global_load_dwordx4 %11, %19, off offset:704 sc0\n\t" \
        "global_load_dwordx4 %12, %19, off offset:768 sc0\n\t" \
        "global_load_dwordx4 %13, %19, off offset:832 sc0\n\t" \
        "global_load_dwordx4 %14, %19, off offset:896 sc0\n\t" \
        "global_load_dwordx4 %15, %19, off offset:960 sc0\n\t" \
        "global_load_dwordx4 %16, %19, off offset:1024 sc0\n\t" \
        "global_load_dword %17, %20, off sc0\n\t" \
        "global_load_ubyte %18, %21, off sc0" \
        : "=&v"(b0), "=&v"(b1), "=&v"(b2), "=&v"(b3), "=&v"(b4), "=&v"(b5), \
          "=&v"(b6), "=&v"(b7), "=&v"(b8), "=&v"(b9), "=&v"(b10), "=&v"(b11), \
          "=&v"(b12), "=&v"(b13), "=&v"(b14), "=&v"(b15), "=&v"(b16), \
          "=&v"(tvr), "=&v"(kfr) \
        : "v"(BP), "v"(TVA), "v"(KFA) \
        : "memory"); \
    f32x4 acc0 = {}, acc1 = {}, acc2 = {}, acc3 = {}; \
    asm volatile("s_waitcnt vmcnt(8)" ::: "memory"); \
    __builtin_amdgcn_sched_barrier(0); \
    KSTEP(b0, 0)  KSTEP(b1, 1)  KSTEP(b2, 2)  KSTEP(b3, 3)  KSTEP(b4, 4) \
    KSTEP(b5, 5)  KSTEP(b6, 6)  KSTEP(b7, 7)  KSTEP(b8, 8) \
    asm volatile("s_waitcnt vmcnt(0)" ::: "memory"); \
    __builtin_amdgcn_sched_barrier(0); \
    KSTEP(b9, 9)  KSTEP(b10, 10) KSTEP(b11, 11) KSTEP(b12, 12) \
    KSTEP(b13, 13) KSTEP(b14, 14) KSTEP(b15, 15) KSTEP(b16, 16) \
    if (!kh) { redv[(0 + wm) * 64 + lane] = acc2; redv[(4 + wm) * 64 + lane] = acc3; } \
    else     { redv[(8 + wm) * 64 + lane] = acc0; redv[(12 + wm) * 64 + lane] = acc1; } \
    __syncthreads(); \
    float tvf = tvr; int kf = (WARMF) ? (int)kfr : 0; \
    f32x4 zA, zB; \
    if (!kh) { zA = acc0 + redv[(8 + wm) * 64 + lane]; zB = acc1 + redv[(12 + wm) * 64 + lane]; } \
    else     { zA = acc2 + redv[(0 + wm) * 64 + lane]; zB = acc3 + redv[(4 + wm) * 64 + lane]; } \
    gate_update(zA[0], zA[1], zA[2], zA[3], BiA, BfA, BgA, BoA, PhA, RpA, RoA, K2A, tvf, kf, hA, cA); \
    *(__bf16*)(hstageb + hrowb + colAb) = (__bf16)hA; \
    gate_update(zB[0], zB[1], zB[2], zB[3], BiB, BfB, BgB, BoB, PhB, RpB, RoB, K2B, tvf, kf, hB, cB); \
    *(__bf16*)(hstageb + hrowb + colBb) = (__bf16)hB; \
    __syncthreads(); \
}

#define COPYOUT(AW) { \
    int ml_ = tid >> 2, c4_ = tid & 3; \
    unsigned long long v_ = *(const unsigned long long*)(hstageb + ml_ * 40 + c4_ * 8); \
    __hip_atomic_store((unsigned long long*)&(AW)[(size_t)(gm0 + ml_) * KTOT + 16 + u0 + c4_ * 4], \
                       v_, __ATOMIC_RELAXED, __HIP_MEMORY_SCOPE_AGENT); \
}

__global__ __launch_bounds__(512, 2) void rnn_all(
    const __bf16* __restrict__ Wcat,
    __bf16* __restrict__ Ab0, __bf16* __restrict__ Ab1,
    float* __restrict__ hT, float* __restrict__ a1T,
    const float* __restrict__ bias, const float* __restrict__ period,
    const float* __restrict__ phase, const float* __restrict__ ratio,
    const float* __restrict__ tvx, const unsigned char* __restrict__ kflag,
    const __bf16* __restrict__ xbf,
    const float* __restrict__ w1, const float* __restrict__ b1,
    const float* __restrict__ w2, const float* __restrict__ b2,
    const float* __restrict__ w3, const float* __restrict__ b3,
    const float* __restrict__ wo, const float* __restrict__ bo,
    float* __restrict__ out, unsigned int* ctr) {
    extern __shared__ __align__(16) char smem[];
    __bf16* Ws      = (__bf16*)smem;                 // [64][KP]
    f32x4*  redv    = (f32x4*)(smem + RED_OFF);      // 16 slots x 64 lanes
    float*  redf    = (float*)redv;
    char*   hstageb = smem + HST_OFF;                // 64 rows x 40B

    int b   = blockIdx.x;
    int gb  = b & 3, rb = b >> 2;
    int tid = threadIdx.x;
    int wave = tid >> 6, lane = tid & 63;
    int wm = wave & 3, kh = wave >> 2;
    int l16 = lane & 15, quad = lane >> 4;
    int gm0 = gb * 64, r0 = rb * 64, u0 = rb * 16;

    // one-time: stage Wcat slice into LDS
    for (int i = tid; i < 64 * 136; i += 512) {
        int rr = i / 136, cc = i - rr * 136;
        *(bf16x8*)&Ws[rr * KP + cc * 8] =
            *(const bf16x8*)&Wcat[(size_t)(r0 + rr) * KTOT + cc * 8];
    }

    int mm = gm0 + wm * 16 + l16;
    int uuA = u0 + kh * 8 + quad, uuB = uuA + 4;
    float BiA = bias[uuA],             BiB = bias[uuB];
    float BfA = bias[UNITS + uuA],     BfB = bias[UNITS + uuB];
    float BgA = bias[2 * UNITS + uuA], BgB = bias[2 * UNITS + uuB];
    float BoA = bias[3 * UNITS + uuA], BoB = bias[3 * UNITS + uuB];
    float PhA = phase[uuA], PhB = phase[uuB];
    float RpA = 1.f / period[uuA], RpB = 1.f / period[uuB];
    float RoA = ratio[uuA], RoB = ratio[uuB];
    float K2A = 2.f / RoA,  K2B = 2.f / RoB;
    float hA = 0.f, cA = 0.f, hB = 0.f, cB = 0.f;

    const __bf16* wsbase = Ws + (size_t)l16 * KP + quad * 8 + kh * 544;
    const __bf16* ba0 = Ab0 + (size_t)mm * KTOT + quad * 8 + kh * 544;
    const __bf16* ba1 = Ab1 + (size_t)mm * KTOT + quad * 8 + kh * 544;
    int hrowb = (wm * 16 + l16) * 40;
    int colAb = (kh * 8 + quad) * 2;
    int colBb = colAb + 8;
    unsigned int* gctr = ctr + TSTEPS * 4 * 16;

    __syncthreads();   // Ws ready

    // ---------------- warm phase: 512 steps ----------------
#pragma unroll 1
    for (int t = 0; t < TSTEPS; ++t) {
        const __bf16* bp = (t & 1) ? ba1 : ba0;
        __bf16* Aw = (t & 1) ? Ab0 : Ab1;
        const float* tva = tvx + (size_t)t * BATCH + mm;
        const unsigned char* kfa = kflag + (size_t)t * BATCH + mm;
        STEP_CORE(bp, tva, kfa, 1)
        if (tid < 256) {
            COPYOUT(Aw)
        } else if (t + 1 < TSTEPS) {
            // stage next-step x: 256 threads, 64 rows x 4 quads x 4 bf16 = 16 feats
            int i = tid - 256;
            int row = i >> 2, q = i & 3;
            unsigned long long v = *(const unsigned long long*)
                &xbf[((size_t)(t + 1) * BATCH + gm0 + row) * 16 + q * 4];
            __hip_atomic_store(
                (unsigned long long*)&Aw[(size_t)(gm0 + row) * KTOT + q * 4],
                v, __ATOMIC_RELAXED, __HIP_MEMORY_SCOPE_AGENT);
        }
        if (t + 1 < TSTEPS) {
            unsigned int* cp_ = ctr + ((size_t)t * 4 + gb) * 16;
            BAR_SYNC(cp_, 64u)
        }
    }

    // ---------------- AR phase: 24 iterations ----------------
    int par = 0;   // parity the next AR step READS (after 512 warm steps)
    int gi = 0;
#pragma unroll 1
    for (int s = 0; s < OUTSTEPS; ++s) {
        // dump h state (fp32, transposed [u][m]) for dense1
        __hip_atomic_store(&hT[(size_t)uuA * BATCH + mm], hA,
                           __ATOMIC_RELAXED, __HIP_MEMORY_SCOPE_AGENT);
        __hip_atomic_store(&hT[(size_t)uuB * BATCH + mm], hB,
                           __ATOMIC_RELAXED, __HIP_MEMORY_SCOPE_AGENT);
        { unsigned int* cp_ = gctr + (size_t)gi * 16; gi++; BAR_SYNC(cp_, 256u) }

        // dense1: a1T[j][m] = tanh(sum_k hT[k][m] * w1[k][j] + b1[j])
        // block covers j = rb*4..+3, m = gm0..+63; waves split k (128 each).
        {
            const float* hp0 = hT + (size_t)(wave * 128) * BATCH + gm0 + lane;
            const float* hp1 = hp0 + 4 * BATCH;
            const float* wp0 = w1 + (size_t)(wave * 128) * 256 + rb * 4;
            const float* wp1 = wp0 + 4 * 256;
            float d0 = 0.f, d1 = 0.f, d2 = 0.f, d3 = 0.f;
#pragma unroll 1
            for (int it = 0; it < 16; ++it) {
                float x0, x1, x2, x3, x4, x5, x6, x7;
                f32x4 w0_, w1_, w2_, w3_, w4_, w5_, w6_, w7_;
                asm volatile(
                    "global_load_dword %0, %16, off sc0\n\t"
                    "global_load_dword %1, %16, off offset:1024 sc0\n\t"
                    "global_load_dword %2, %16, off offset:2048 sc0\n\t"
                    "global_load_dword %3, %16, off offset:3072 sc0\n\t"
                    "global_load_dword %4, %17, off sc0\n\t"
                    "global_load_dword %5, %17, off offset:1024 sc0\n\t"
                    "global_load_dword %6, %17, off offset:2048 sc0\n\t"
                    "global_load_dword %7, %17, off offset:3072 sc0\n\t"
                    "global_load_dwordx4 %8, %18, off\n\t"
                    "global_load_dwordx4 %9, %18, off offset:1024\n\t"
                    "global_load_dwordx4 %10, %18, off offset:2048\n\t"
                    "global_load_dwordx4 %11, %18, off offset:3072\n\t"
                    "global_load_dwordx4 %12, %19, off\n\t"
                    "global_load_dwordx4 %13, %19, off offset:1024\n\t"
                    "global_load_dwordx4 %14, %19, off offset:2048\n\t"
                    "global_load_dwordx4 %15, %19, off offset:3072"
                    : "=&v"(x0), "=&v"(x1), "=&v"(x2), "=&v"(x3),
                      "=&v"(x4), "=&v"(x5), "=&v"(x6), "=&v"(x7),
                      "=&v"(w0_), "=&v"(w1_), "=&v"(w2_), "=&v"(w3_),
                      "=&v"(w4_), "=&v"(w5_), "=&v"(w6_), "=&v"(w7_)
                    : "v"(hp0), "v"(hp1), "v"(wp0), "v"(wp1)
                    : "memory");
                asm volatile("s_waitcnt vmcnt(0)" ::: "memory");
                __builtin_amdgcn_sched_barrier(0);
                d0 += x0 * w0_[0]; d1 += x0 * w0_[1]; d2 += x0 * w0_[2]; d3 += x0 * w0_[3];
                d0 += x1 * w1_[0]; d1 += x1 * w1_[1]; d2 += x1 * w1_[2]; d3 += x1 * w1_[3];
                d0 += x2 * w2_[0]; d1 += x2 * w2_[1]; d2 += x2 * w2_[2]; d3 += x2 * w2_[3];
                d0 += x3 * w3_[0]; d1 += x3 * w3_[1]; d2 += x3 * w3_[2]; d3 += x3 * w3_[3];
                d0 += x4 * w4_[0]; d1 += x4 * w4_[1]; d2 += x4 * w4_[2]; d3 += x4 * w4_[3];
                d0 += x5 * w5_[0]; d1 += x5 * w5_[1]; d2 += x5 * w5_[2]; d3 += x5 * w5_[3];
                d0 += x6 * w6_[0]; d1 += x6 * w6_[1]; d2 += x6 * w6_[2]; d3 += x6 * w6_[3];
                d0 += x7 * w7_[0]; d1 += x7 * w7_[1]; d2 += x7 * w7_[2]; d3 += x7 * w7_[3];
                hp0 += 8 * BATCH; hp1 += 8 * BATCH;
                wp0 += 8 * 256;   wp1 += 8 * 256;
            }
            redf[wave * 256 + 0 * 64 + lane] = d0;
            redf[wave * 256 + 1 * 64 + lane] = d1;
            redf[wave * 256 + 2 * 64 + lane] = d2;
            redf[wave * 256 + 3 * 64 + lane] = d3;
            __syncthreads();
            if (tid < 256) {
                int q = tid >> 6, ml2 = tid & 63;
                float sum = 0.f;
#pragma unroll
                for (int w = 0; w < 8; ++w) sum += redf[w * 256 + q * 64 + ml2];
                sum = tanhf_(sum + b1[rb * 4 + q]);
                __hip_atomic_store(&a1T[(size_t)(rb * 4 + q) * 256 + gm0 + ml2], sum,
                                   __ATOMIC_RELAXED, __HIP_MEMORY_SCOPE_AGENT);
            }
        }
        { unsigned int* cp_ = gctr + (size_t)gi * 16; gi++; BAR_SYNC(cp_, 256u) }

        // dense tail (32 blocks: rb<8): L2,L3,L4 for rows m0t..m0t+7
        if (rb < 8) {
            int m0t = gb * 64 + rb * 8;
            float* a1s = (float*)redv;        // [8][256]
            float* a2s = a1s + 8 * 256;       // [8][128]
            float* a3s = a2s + 8 * 128;       // [8][64]
            {
                float v0, v1, v2, v3;
                int i0 = tid, i1 = tid + 512, i2 = tid + 1024, i3 = tid + 1536;
                const float* p0 = a1T + (size_t)(i0 >> 3) * 256 + m0t + (i0 & 7);
                const float* p1 = a1T + (size_t)(i1 >> 3) * 256 + m0t + (i1 & 7);
                const float* p2 = a1T + (size_t)(i2 >> 3) * 256 + m0t + (i2 & 7);
                const float* p3 = a1T + (size_t)(i3 >> 3) * 256 + m0t + (i3 & 7);
                asm volatile(
                    "global_load_dword %0, %4, off sc0\n\t"
                    "global_load_dword %1, %5, off sc0\n\t"
                    "global_load_dword %2, %6, off sc0\n\t"
                    "global_load_dword %3, %7, off sc0"
                    : "=&v"(v0), "=&v"(v1), "=&v"(v2), "=&v"(v3)
                    : "v"(p0), "v"(p1), "v"(p2), "v"(p3) : "memory");
                asm volatile("s_waitcnt vmcnt(0)" ::: "memory");
                __builtin_amdgcn_sched_barrier(0);
                a1s[(i0 & 7) * 256 + (i0 >> 3)] = v0;
                a1s[(i1 & 7) * 256 + (i1 >> 3)] = v1;
                a1s[(i2 & 7) * 256 + (i2 >> 3)] = v2;
                a1s[(i3 & 7) * 256 + (i3 >> 3)] = v3;
            }
            __syncthreads();
            if (tid < 256) {   // L2: 256 -> 128
                int j = tid & 127, r2 = tid >> 7;
                float acc[4] = {0.f, 0.f, 0.f, 0.f};
                for (int k = 0; k < 256; k++) {
                    float w = w2[(size_t)k * 128 + j];
#pragma unroll
                    for (int q = 0; q < 4; q++) acc[q] += a1s[(r2 * 4 + q) * 256 + k] * w;
                }
                float bb = b2[j];
#pragma unroll
                for (int q = 0; q < 4; q++) a2s[(r2 * 4 + q) * 128 + j] = tanhf_(acc[q] + bb);
            }
            __syncthreads();
            if (tid < 256) {   // L3: 128 -> 64
                int j = tid & 63, r2 = tid >> 6;
                float acc[2] = {0.f, 0.f};
                for (int k = 0; k < 128; k++) {
                    float w = w3[(size_t)k * 64 + j];
#pragma unroll
                    for (int q = 0; q < 2; q++) acc[q] += a2s[(r2 * 2 + q) * 128 + k] * w;
                }
                float bb = b3[j];
#pragma unroll
                for (int q = 0; q < 2; q++) a3s[(r2 * 2 + q) * 64 + j] = tanhf_(acc[q] + bb);
            }
            __syncthreads();
            if (tid < 128) {   // L4: 64 -> 16, write out + pout scratch
                int j = tid & 15, r = tid >> 4;
                float accv = 0.f;
                for (int k = 0; k < 64; k++) accv += a3s[r * 64 + k] * wo[(size_t)k * 16 + j];
                float v = accv + bo[j];
                __hip_atomic_store(&out[(size_t)(m0t + r) * (OUTSTEPS * FEAT) + s * FEAT + j],
                                   v, __ATOMIC_RELAXED, __HIP_MEMORY_SCOPE_AGENT);
                a1s[r * 16 + j] = v;
            }
            __syncthreads();
            if (tid < 64) {    // pack pred -> bf16 x-cols of buffer `par`
                int r = tid >> 3, jp = tid & 7;
                __bf16 lo = (__bf16)a1s[r * 16 + jp * 2];
                __bf16 hi = (__bf16)a1s[r * 16 + jp * 2 + 1];
                unsigned int pv = (unsigned int)(*(unsigned short*)&lo) |
                                  ((unsigned int)(*(unsigned short*)&hi) << 16);
                __bf16* xdst = (par ? Ab1 : Ab0) + (size_t)(m0t + r) * KTOT + jp * 2;
                __hip_atomic_store((unsigned int*)xdst, pv,
                                   __ATOMIC_RELAXED, __HIP_MEMORY_SCOPE_AGENT);
            }
        }
        { unsigned int* cp_ = gctr + (size_t)gi * 16; gi++; BAR_SYNC(cp_, 256u) }

        // AR step
        if (s < OUTSTEPS - 1) {
            const __bf16* bp = par ? ba1 : ba0;
            __bf16* Aw = par ? Ab0 : Ab1;
            const float* tva = out + (size_t)mm * (OUTSTEPS * FEAT) + s * FEAT;
            STEP_CORE(bp, tva, tva, 0)
            if (tid < 256) {
                COPYOUT(Aw)
            }
            par ^= 1;
        }
    }
}

// ---------------------------------------------------------------------------
extern "C" void kernel_launch(void* const* d_in, const int* in_sizes, int n_in,
                              void* d_out, int out_size, void* d_ws, size_t ws_size,
                              hipStream_t stream) {
    (void)in_sizes; (void)n_in; (void)out_size; (void)ws_size;
    const float* x      = (const float*)d_in[0];
    const float* kern   = (const float*)d_in[1];
    const float* rec    = (const float*)d_in[2];
    const float* bias   = (const float*)d_in[3];
    const float* period = (const float*)d_in[4];
    const float* phase  = (const float*)d_in[5];
    const float* ratio  = (const float*)d_in[6];
    const float* w1 = (const float*)d_in[7];
    const float* b1 = (const float*)d_in[8];
    const float* w2 = (const float*)d_in[9];
    const float* b2 = (const float*)d_in[10];
    const float* w3 = (const float*)d_in[11];
    const float* b3 = (const float*)d_in[12];
    const float* wo = (const float*)d_in[13];
    const float* bo = (const float*)d_in[14];
    float* out = (float*)d_out;

    char* ws = (char*)d_ws;
    const size_t WCAT_B = (size_t)NROWS * KTOT * 2;        // 8,912,896
    const size_t AB_B   = (size_t)BATCH * KTOT * 2;        // 557,056
    __bf16* Wcat = (__bf16*)ws;
    __bf16* Ab0  = (__bf16*)(ws + WCAT_B);
    __bf16* Ab1  = (__bf16*)(ws + WCAT_B + AB_B);
    float*  hT   = (float*)(ws + WCAT_B + 2 * AB_B);
    float*  a1T  = hT + (size_t)BATCH * UNITS;
    float*  tvx  = a1T + (size_t)BATCH * 256;
    __bf16* xbf  = (__bf16*)(tvx + (size_t)TSTEPS * BATCH);
    unsigned char* kflag = (unsigned char*)(xbf + (size_t)TSTEPS * BATCH * 16);
    unsigned int*  ctr   = (unsigned int*)(kflag + (size_t)TSTEPS * BATCH);

    (void)hipFuncSetAttribute((const void*)rnn_all,
                              hipFuncAttributeMaxDynamicSharedMemorySize,
                              (int)SMEM_BYTES);

    prep_weights<<<dim3(64, 17), 256, 0, stream>>>(kern, rec, Wcat);
    prep_state<<<512, 256, 0, stream>>>(x, Ab0, Ab1, hT, ctr);
    prep_tv<<<256, 256, 0, stream>>>(x, tvx, kflag, xbf);

    rnn_all<<<dim3(256), dim3(512), SMEM_BYTES, stream>>>(
        Wcat, Ab0, Ab1, hT, a1T, bias, period, phase, ratio,
        tvx, kflag, xbf, w1, b1, w2, b2, w3, b3, wo, bo, out, ctr);
}

// Round 6
// 5309.594 us; speedup vs baseline: 2.6144x; 2.6144x over previous
//
#include <hip/hip_runtime.h>
#include <hip/hip_bf16.h>

#define UNITS 1024
#define FEAT  16
#define TSTEPS 512
#define OUTSTEPS 24
#define BATCH 256
#define KTOT  1088   // 16 (x) + 1024 (h) + 48 pad
#define KP    1096   // padded LDS stride (2192B), conflict-reduced b128
#define NROWS 4096   // 4*UNITS, reordered r = 4*u + gate

// LDS: Ws [64][KP] bf16 (140288) + red 16KB + hstage 64 rows x 40B (2560)
#define RED_OFF    (64 * KP * 2)
#define HST_OFF    (RED_OFF + 16384)
#define SMEM_BYTES (HST_OFF + 2560)   // 159,232 <= 160 KiB

#define NGBAR   96
#define CTR_TOT ((TSTEPS * 4 + NGBAR) * 16)

typedef __bf16 bf16x8 __attribute__((ext_vector_type(8)));
typedef float  f32x4  __attribute__((ext_vector_type(4)));

__device__ __forceinline__ float sigmoidf_(float x) { return 1.f / (1.f + __expf(-x)); }
__device__ __forceinline__ float tanhf_(float x)    { return 1.f - 2.f / (__expf(2.f * x) + 1.f); }

// ---------------------------------------------------------------------------
// Build Wcat_T[r][k] (bf16, row-major, stride KTOT), r = 4*u + g.
// ---------------------------------------------------------------------------
__global__ __launch_bounds__(256) void prep_weights(const float* __restrict__ kern,
                                                    const float* __restrict__ rec,
                                                    __bf16* __restrict__ Wcat) {
    __shared__ __align__(16) __bf16 tile[64][72];
    int r0 = blockIdx.x * 64;
    int k0 = blockIdx.y * 64;
    int t  = threadIdx.x;
    int c_off = t & 63;
    int k_grp = t >> 6;
    int g = c_off >> 4, ui = c_off & 15;
    int u0 = r0 >> 2;
    int c  = g * 1024 + u0 + ui;
    int rl = 4 * ui + g;
    for (int i = 0; i < 16; i++) {
        int k = k0 + k_grp * 16 + i;
        float v = 0.f;
        if (k < 16)        v = kern[(size_t)k * NROWS + c];
        else if (k < 1040) v = rec[(size_t)(k - 16) * NROWS + c];
        tile[rl][k_grp * 16 + i] = (__bf16)v;
    }
    __syncthreads();
    int rl2 = t >> 2, ch = t & 3;
    bf16x8* dst = (bf16x8*)(Wcat + (size_t)(r0 + rl2) * KTOT + k0 + ch * 16);
    const bf16x8* src = (const bf16x8*)&tile[rl2][ch * 16];
    dst[0] = src[0];
    dst[1] = src[1];
}

// ---------------------------------------------------------------------------
// Zero hT, zero+x-init Abuf buffers, zero barrier counters.
// ---------------------------------------------------------------------------
__global__ __launch_bounds__(256) void prep_state(const float* __restrict__ x,
                                                  __bf16* __restrict__ Ab0,
                                                  __bf16* __restrict__ Ab1,
                                                  float* __restrict__ hT,
                                                  unsigned int* __restrict__ ctr) {
    int tid = blockIdx.x * 256 + threadIdx.x;
    int np  = gridDim.x * 256;
    for (int i = tid; i < BATCH * UNITS; i += np) hT[i] = 0.f;
    const int AB = BATCH * KTOT;
    for (int i = tid; i < 2 * AB; i += np) {
        int which = (i < AB) ? 0 : 1;
        int p = i - which * AB;
        int col = p % KTOT;
        int m   = p / KTOT;
        __bf16 v = (__bf16)0.f;
        if (which == 0 && col < FEAT) v = (__bf16)x[(size_t)m * TSTEPS * FEAT + col];
        if (which == 0) Ab0[p] = v; else Ab1[p] = v;
    }
    for (int i = tid; i < CTR_TOT; i += np) ctr[i] = 0u;
}

// ---------------------------------------------------------------------------
// Precompute per-(t,m): tv, keep-flag, bf16 x table.
// ---------------------------------------------------------------------------
__global__ __launch_bounds__(256) void prep_tv(const float* __restrict__ x,
                                               float* __restrict__ tvx,
                                               unsigned char* __restrict__ kflag,
                                               __bf16* __restrict__ xbf) {
    int m = blockIdx.x;
    for (int t = threadIdx.x; t < TSTEPS; t += 256) {
        const float* row = x + ((size_t)m * TSTEPS + t) * FEAT;
        f32x4 v0 = *(const f32x4*)row;
        f32x4 v1 = *(const f32x4*)(row + 4);
        f32x4 v2 = *(const f32x4*)(row + 8);
        f32x4 v3 = *(const f32x4*)(row + 12);
        bool keep = true;
#pragma unroll
        for (int i = 0; i < 4; ++i)
            keep = keep && (v0[i] == -1.f) && (v1[i] == -1.f) &&
                   (v2[i] == -1.f) && (v3[i] == -1.f);
        tvx[(size_t)t * BATCH + m]   = v0[0];
        kflag[(size_t)t * BATCH + m] = keep ? 1 : 0;
        __bf16* xo = xbf + ((size_t)t * BATCH + m) * 16;
        bf16x8 o0, o1;
#pragma unroll
        for (int i = 0; i < 4; ++i) { o0[i] = (__bf16)v0[i]; o0[4 + i] = (__bf16)v1[i]; }
#pragma unroll
        for (int i = 0; i < 4; ++i) { o1[i] = (__bf16)v2[i]; o1[4 + i] = (__bf16)v3[i]; }
        *(bf16x8*)xo = o0;
        *(bf16x8*)(xo + 8) = o1;
    }
}

// ---------------------------------------------------------------------------
__device__ __forceinline__ void gate_update(
    float z0, float z1, float z2, float z3,
    float bi, float bf, float bg, float bo,
    float ph, float rp, float ro, float k2,
    float tv, int kf, float& h, float& c) {
    float zi = z0 + bi, zf = z1 + bf, zg = z2 + bg, zo = z3 + bo;
    float ig = sigmoidf_(zi), fg = sigmoidf_(zf), og = sigmoidf_(zo);
    float gv = tanhf_(zg);
    float nc = fg * c + ig * gv;
    float nh = og * tanhf_(nc);
    float cr = (tv - ph) * rp;
    cr = cr - floorf(cr);
    float kup = cr * k2;
    float kk = (cr < ro) ? (2.f - kup) : (0.001f * cr);
    kk = (cr < 0.5f * ro) ? kup : kk;
    float ho = kk * nh + (1.f - kk) * h;
    float co = kk * nc + (1.f - kk) * c;
    if (kf) { ho = h; co = c; }
    h = ho; c = co;
}

// ---------------------------------------------------------------------------
// Mega persistent kernel: 512 warm steps (per-group barrier) + 24 AR
// iterations (dense1 + dense tail + AR step, grid barriers). 256 blocks x
// 512 thr, 1 block/CU (LDS-forced => all co-resident).
// Coherence (R2-proven, fence-free): all cross-block-communicated stores are
// sc1 write-through atomics (straight to the coherence point; L2 never
// dirty); all cross-block-communicated loads are `sc0 sc1` (bypass possibly-
// stale L1/L2, read the coherence point). NO buffer_inv / buffer_wbl2
// anywhere (R5 measured the per-block inv at +17 us/step). Read-only data
// (weights, bias tables, xbf, tvx) uses normally cached loads.
// ---------------------------------------------------------------------------
#define KSTEP(BF, KT) { \
    const __bf16* ap_ = wsbase + (KT) * 32; \
    bf16x8 a0_ = *(const bf16x8*)(ap_); \
    bf16x8 a1_ = *(const bf16x8*)(ap_ + 16 * KP); \
    bf16x8 a2_ = *(const bf16x8*)(ap_ + 32 * KP); \
    bf16x8 a3_ = *(const bf16x8*)(ap_ + 48 * KP); \
    acc0 = __builtin_amdgcn_mfma_f32_16x16x32_bf16(a0_, BF, acc0, 0, 0, 0); \
    acc1 = __builtin_amdgcn_mfma_f32_16x16x32_bf16(a1_, BF, acc1, 0, 0, 0); \
    acc2 = __builtin_amdgcn_mfma_f32_16x16x32_bf16(a2_, BF, acc2, 0, 0, 0); \
    acc3 = __builtin_amdgcn_mfma_f32_16x16x32_bf16(a3_, BF, acc3, 0, 0, 0); \
}

#define BAR_SYNC(CP, COUNT) \
    __syncthreads(); \
    if (tid == 0) { \
        __hip_atomic_fetch_add((CP), 1u, __ATOMIC_RELAXED, __HIP_MEMORY_SCOPE_AGENT); \
        while (__hip_atomic_load((CP), __ATOMIC_RELAXED, __HIP_MEMORY_SCOPE_AGENT) < (COUNT)) \
            __builtin_amdgcn_s_sleep(2); \
    } \
    __syncthreads();

#define STEP_CORE(BP, TVA, KFA, WARMF) { \
    bf16x8 b0, b1, b2, b3, b4, b5, b6, b7, b8, b9, b10, b11, b12, b13, b14, b15, b16; \
    float tvr; unsigned int kfr; \
    asm volatile( \
        "global_load_dwordx4 %0, %19, off sc0 sc1\n\t" \
        "global_load_dwordx4 %1, %19, off offset:64 sc0 sc1\n\t" \
        "global_load_dwordx4 %2, %19, off offset:128 sc0 sc1\n\t" \
        "global_load_dwordx4 %3, %19, off offset:192 sc0 sc1\n\t" \
        "global_load_dwordx4 %4, %19, off offset:256 sc0 sc1\n\t" \
        "global_load_dwordx4 %5, %19, off offset:320 sc0 sc1\n\t" \
        "global_load_dwordx4 %6, %19, off offset:384 sc0 sc1\n\t" \
        "global_load_dwordx4 %7, %19, off offset:448 sc0 sc1\n\t" \
        "global_load_dwordx4 %8, %19, off offset:512 sc0 sc1\n\t" \
        "global_load_dwordx4 %9, %19, off offset:576 sc0 sc1\n\t" \
        "global_load_dwordx4 %10, %19, off offset:640 sc0 sc1\n\t" \
        "global_load_dwordx4 %11, %19, off offset:704 sc0 sc1\n\t" \
        "global_load_dwordx4 %12, %19, off offset:768 sc0 sc1\n\t" \
        "global_load_dwordx4 %13, %19, off offset:832 sc0 sc1\n\t" \
        "global_load_dwordx4 %14, %19, off offset:896 sc0 sc1\n\t" \
        "global_load_dwordx4 %15, %19, off offset:960 sc0 sc1\n\t" \
        "global_load_dwordx4 %16, %19, off offset:1024 sc0 sc1\n\t" \
        "global_load_dword %17, %20, off sc0 sc1\n\t" \
        "global_load_ubyte %18, %21, off sc0 sc1" \
        : "=&v"(b0), "=&v"(b1), "=&v"(b2), "=&v"(b3), "=&v"(b4), "=&v"(b5), \
          "=&v"(b6), "=&v"(b7), "=&v"(b8), "=&v"(b9), "=&v"(b10), "=&v"(b11), \
          "=&v"(b12), "=&v"(b13), "=&v"(b14), "=&v"(b15), "=&v"(b16), \
          "=&v"(tvr), "=&v"(kfr) \
        : "v"(BP), "v"(TVA), "v"(KFA) \
        : "memory"); \
    f32x4 acc0 = {}, acc1 = {}, acc2 = {}, acc3 = {}; \
    asm volatile("s_waitcnt vmcnt(8)" ::: "memory"); \
    __builtin_amdgcn_sched_barrier(0); \
    KSTEP(b0, 0)  KSTEP(b1, 1)  KSTEP(b2, 2)  KSTEP(b3, 3)  KSTEP(b4, 4) \
    KSTEP(b5, 5)  KSTEP(b6, 6)  KSTEP(b7, 7)  KSTEP(b8, 8) \
    asm volatile("s_waitcnt vmcnt(0)" ::: "memory"); \
    __builtin_amdgcn_sched_barrier(0); \
    KSTEP(b9, 9)  KSTEP(b10, 10) KSTEP(b11, 11) KSTEP(b12, 12) \
    KSTEP(b13, 13) KSTEP(b14, 14) KSTEP(b15, 15) KSTEP(b16, 16) \
    if (!kh) { redv[(0 + wm) * 64 + lane] = acc2; redv[(4 + wm) * 64 + lane] = acc3; } \
    else     { redv[(8 + wm) * 64 + lane] = acc0; redv[(12 + wm) * 64 + lane] = acc1; } \
    __syncthreads(); \
    float tvf = tvr; int kf = (WARMF) ? (int)kfr : 0; \
    f32x4 zA, zB; \
    if (!kh) { zA = acc0 + redv[(8 + wm) * 64 + lane]; zB = acc1 + redv[(12 + wm) * 64 + lane]; } \
    else     { zA = acc2 + redv[(0 + wm) * 64 + lane]; zB = acc3 + redv[(4 + wm) * 64 + lane]; } \
    gate_update(zA[0], zA[1], zA[2], zA[3], BiA, BfA, BgA, BoA, PhA, RpA, RoA, K2A, tvf, kf, hA, cA); \
    *(__bf16*)(hstageb + hrowb + colAb) = (__bf16)hA; \
    gate_update(zB[0], zB[1], zB[2], zB[3], BiB, BfB, BgB, BoB, PhB, RpB, RoB, K2B, tvf, kf, hB, cB); \
    *(__bf16*)(hstageb + hrowb + colBb) = (__bf16)hB; \
    __syncthreads(); \
}

#define COPYOUT(AW) { \
    int ml_ = tid >> 2, c4_ = tid & 3; \
    unsigned long long v_ = *(const unsigned long long*)(hstageb + ml_ * 40 + c4_ * 8); \
    __hip_atomic_store((unsigned long long*)&(AW)[(size_t)(gm0 + ml_) * KTOT + 16 + u0 + c4_ * 4], \
                       v_, __ATOMIC_RELAXED, __HIP_MEMORY_SCOPE_AGENT); \
}

__global__ __launch_bounds__(512, 2) void rnn_all(
    const __bf16* __restrict__ Wcat,
    __bf16* __restrict__ Ab0, __bf16* __restrict__ Ab1,
    float* __restrict__ hT, float* __restrict__ a1T,
    const float* __restrict__ bias, const float* __restrict__ period,
    const float* __restrict__ phase, const float* __restrict__ ratio,
    const float* __restrict__ tvx, const unsigned char* __restrict__ kflag,
    const __bf16* __restrict__ xbf,
    const float* __restrict__ w1, const float* __restrict__ b1,
    const float* __restrict__ w2, const float* __restrict__ b2,
    const float* __restrict__ w3, const float* __restrict__ b3,
    const float* __restrict__ wo, const float* __restrict__ bo,
    float* __restrict__ out, unsigned int* ctr) {
    extern __shared__ __align__(16) char smem[];
    __bf16* Ws      = (__bf16*)smem;                 // [64][KP]
    f32x4*  redv    = (f32x4*)(smem + RED_OFF);      // 16 slots x 64 lanes
    float*  redf    = (float*)redv;
    char*   hstageb = smem + HST_OFF;                // 64 rows x 40B

    int b   = blockIdx.x;
    int gb  = b & 3, rb = b >> 2;
    int tid = threadIdx.x;
    int wave = tid >> 6, lane = tid & 63;
    int wm = wave & 3, kh = wave >> 2;
    int l16 = lane & 15, quad = lane >> 4;
    int gm0 = gb * 64, r0 = rb * 64, u0 = rb * 16;

    // one-time: stage Wcat slice into LDS
    for (int i = tid; i < 64 * 136; i += 512) {
        int rr = i / 136, cc = i - rr * 136;
        *(bf16x8*)&Ws[rr * KP + cc * 8] =
            *(const bf16x8*)&Wcat[(size_t)(r0 + rr) * KTOT + cc * 8];
    }

    int mm = gm0 + wm * 16 + l16;
    int uuA = u0 + kh * 8 + quad, uuB = uuA + 4;
    float BiA = bias[uuA],             BiB = bias[uuB];
    float BfA = bias[UNITS + uuA],     BfB = bias[UNITS + uuB];
    float BgA = bias[2 * UNITS + uuA], BgB = bias[2 * UNITS + uuB];
    float BoA = bias[3 * UNITS + uuA], BoB = bias[3 * UNITS + uuB];
    float PhA = phase[uuA], PhB = phase[uuB];
    float RpA = 1.f / period[uuA], RpB = 1.f / period[uuB];
    float RoA = ratio[uuA], RoB = ratio[uuB];
    float K2A = 2.f / RoA,  K2B = 2.f / RoB;
    float hA = 0.f, cA = 0.f, hB = 0.f, cB = 0.f;

    const __bf16* wsbase = Ws + (size_t)l16 * KP + quad * 8 + kh * 544;
    const __bf16* ba0 = Ab0 + (size_t)mm * KTOT + quad * 8 + kh * 544;
    const __bf16* ba1 = Ab1 + (size_t)mm * KTOT + quad * 8 + kh * 544;
    int hrowb = (wm * 16 + l16) * 40;
    int colAb = (kh * 8 + quad) * 2;
    int colBb = colAb + 8;
    unsigned int* gctr = ctr + TSTEPS * 4 * 16;

    __syncthreads();   // Ws ready

    // ---------------- warm phase: 512 steps ----------------
#pragma unroll 1
    for (int t = 0; t < TSTEPS; ++t) {
        const __bf16* bp = (t & 1) ? ba1 : ba0;
        __bf16* Aw = (t & 1) ? Ab0 : Ab1;
        const float* tva = tvx + (size_t)t * BATCH + mm;
        const unsigned char* kfa = kflag + (size_t)t * BATCH + mm;
        STEP_CORE(bp, tva, kfa, 1)
        if (tid < 256) {
            COPYOUT(Aw)
        } else if (t + 1 < TSTEPS) {
            // stage next-step x: 256 threads, 64 rows x 4 quads x 4 bf16 = 16 feats
            int i = tid - 256;
            int row = i >> 2, q = i & 3;
            unsigned long long v = *(const unsigned long long*)
                &xbf[((size_t)(t + 1) * BATCH + gm0 + row) * 16 + q * 4];
            __hip_atomic_store(
                (unsigned long long*)&Aw[(size_t)(gm0 + row) * KTOT + q * 4],
                v, __ATOMIC_RELAXED, __HIP_MEMORY_SCOPE_AGENT);
        }
        if (t + 1 < TSTEPS) {
            unsigned int* cp_ = ctr + ((size_t)t * 4 + gb) * 16;
            BAR_SYNC(cp_, 64u)
        }
    }

    // ---------------- AR phase: 24 iterations ----------------
    int par = 0;   // parity the next AR step READS (after 512 warm steps)
    int gi = 0;
#pragma unroll 1
    for (int s = 0; s < OUTSTEPS; ++s) {
        // dump h state (fp32, transposed [u][m]) for dense1
        __hip_atomic_store(&hT[(size_t)uuA * BATCH + mm], hA,
                           __ATOMIC_RELAXED, __HIP_MEMORY_SCOPE_AGENT);
        __hip_atomic_store(&hT[(size_t)uuB * BATCH + mm], hB,
                           __ATOMIC_RELAXED, __HIP_MEMORY_SCOPE_AGENT);
        { unsigned int* cp_ = gctr + (size_t)gi * 16; gi++; BAR_SYNC(cp_, 256u) }

        // dense1: a1T[j][m] = tanh(sum_k hT[k][m] * w1[k][j] + b1[j])
        // block covers j = rb*4..+3, m = gm0..+63; waves split k (128 each).
        // hT loads: sc0 sc1 (cross-block data); w1 loads: plain (read-only).
        {
            const float* hp0 = hT + (size_t)(wave * 128) * BATCH + gm0 + lane;
            const float* hp1 = hp0 + 4 * BATCH;
            const float* wp0 = w1 + (size_t)(wave * 128) * 256 + rb * 4;
            const float* wp1 = wp0 + 4 * 256;
            float d0 = 0.f, d1 = 0.f, d2 = 0.f, d3 = 0.f;
#pragma unroll 1
            for (int it = 0; it < 16; ++it) {
                float x0, x1, x2, x3, x4, x5, x6, x7;
                f32x4 w0_, w1_, w2_, w3_, w4_, w5_, w6_, w7_;
                asm volatile(
                    "global_load_dword %0, %16, off sc0 sc1\n\t"
                    "global_load_dword %1, %16, off offset:1024 sc0 sc1\n\t"
                    "global_load_dword %2, %16, off offset:2048 sc0 sc1\n\t"
                    "global_load_dword %3, %16, off offset:3072 sc0 sc1\n\t"
                    "global_load_dword %4, %17, off sc0 sc1\n\t"
                    "global_load_dword %5, %17, off offset:1024 sc0 sc1\n\t"
                    "global_load_dword %6, %17, off offset:2048 sc0 sc1\n\t"
                    "global_load_dword %7, %17, off offset:3072 sc0 sc1\n\t"
                    "global_load_dwordx4 %8, %18, off\n\t"
                    "global_load_dwordx4 %9, %18, off offset:1024\n\t"
                    "global_load_dwordx4 %10, %18, off offset:2048\n\t"
                    "global_load_dwordx4 %11, %18, off offset:3072\n\t"
                    "global_load_dwordx4 %12, %19, off\n\t"
                    "global_load_dwordx4 %13, %19, off offset:1024\n\t"
                    "global_load_dwordx4 %14, %19, off offset:2048\n\t"
                    "global_load_dwordx4 %15, %19, off offset:3072"
                    : "=&v"(x0), "=&v"(x1), "=&v"(x2), "=&v"(x3),
                      "=&v"(x4), "=&v"(x5), "=&v"(x6), "=&v"(x7),
                      "=&v"(w0_), "=&v"(w1_), "=&v"(w2_), "=&v"(w3_),
                      "=&v"(w4_), "=&v"(w5_), "=&v"(w6_), "=&v"(w7_)
                    : "v"(hp0), "v"(hp1), "v"(wp0), "v"(wp1)
                    : "memory");
                asm volatile("s_waitcnt vmcnt(0)" ::: "memory");
                __builtin_amdgcn_sched_barrier(0);
                d0 += x0 * w0_[0]; d1 += x0 * w0_[1]; d2 += x0 * w0_[2]; d3 += x0 * w0_[3];
                d0 += x1 * w1_[0]; d1 += x1 * w1_[1]; d2 += x1 * w1_[2]; d3 += x1 * w1_[3];
                d0 += x2 * w2_[0]; d1 += x2 * w2_[1]; d2 += x2 * w2_[2]; d3 += x2 * w2_[3];
                d0 += x3 * w3_[0]; d1 += x3 * w3_[1]; d2 += x3 * w3_[2]; d3 += x3 * w3_[3];
                d0 += x4 * w4_[0]; d1 += x4 * w4_[1]; d2 += x4 * w4_[2]; d3 += x4 * w4_[3];
                d0 += x5 * w5_[0]; d1 += x5 * w5_[1]; d2 += x5 * w5_[2]; d3 += x5 * w5_[3];
                d0 += x6 * w6_[0]; d1 += x6 * w6_[1]; d2 += x6 * w6_[2]; d3 += x6 * w6_[3];
                d0 += x7 * w7_[0]; d1 += x7 * w7_[1]; d2 += x7 * w7_[2]; d3 += x7 * w7_[3];
                hp0 += 8 * BATCH; hp1 += 8 * BATCH;
                wp0 += 8 * 256;   wp1 += 8 * 256;
            }
            redf[wave * 256 + 0 * 64 + lane] = d0;
            redf[wave * 256 + 1 * 64 + lane] = d1;
            redf[wave * 256 + 2 * 64 + lane] = d2;
            redf[wave * 256 + 3 * 64 + lane] = d3;
            __syncthreads();
            if (tid < 256) {
                int q = tid >> 6, ml2 = tid & 63;
                float sum = 0.f;
#pragma unroll
                for (int w = 0; w < 8; ++w) sum += redf[w * 256 + q * 64 + ml2];
                sum = tanhf_(sum + b1[rb * 4 + q]);
                __hip_atomic_store(&a1T[(size_t)(rb * 4 + q) * 256 + gm0 + ml2], sum,
                                   __ATOMIC_RELAXED, __HIP_MEMORY_SCOPE_AGENT);
            }
        }
        { unsigned int* cp_ = gctr + (size_t)gi * 16; gi++; BAR_SYNC(cp_, 256u) }

        // dense tail (32 blocks: rb<8): L2,L3,L4 for rows m0t..m0t+7
        if (rb < 8) {
            int m0t = gb * 64 + rb * 8;
            float* a1s = (float*)redv;        // [8][256]
            float* a2s = a1s + 8 * 256;       // [8][128]
            float* a3s = a2s + 8 * 128;       // [8][64]
            {
                float v0, v1, v2, v3;
                int i0 = tid, i1 = tid + 512, i2 = tid + 1024, i3 = tid + 1536;
                const float* p0 = a1T + (size_t)(i0 >> 3) * 256 + m0t + (i0 & 7);
                const float* p1 = a1T + (size_t)(i1 >> 3) * 256 + m0t + (i1 & 7);
                const float* p2 = a1T + (size_t)(i2 >> 3) * 256 + m0t + (i2 & 7);
                const float* p3 = a1T + (size_t)(i3 >> 3) * 256 + m0t + (i3 & 7);
                asm volatile(
                    "global_load_dword %0, %4, off sc0 sc1\n\t"
                    "global_load_dword %1, %5, off sc0 sc1\n\t"
                    "global_load_dword %2, %6, off sc0 sc1\n\t"
                    "global_load_dword %3, %7, off sc0 sc1"
                    : "=&v"(v0), "=&v"(v1), "=&v"(v2), "=&v"(v3)
                    : "v"(p0), "v"(p1), "v"(p2), "v"(p3) : "memory");
                asm volatile("s_waitcnt vmcnt(0)" ::: "memory");
                __builtin_amdgcn_sched_barrier(0);
                a1s[(i0 & 7) * 256 + (i0 >> 3)] = v0;
                a1s[(i1 & 7) * 256 + (i1 >> 3)] = v1;
                a1s[(i2 & 7) * 256 + (i2 >> 3)] = v2;
                a1s[(i3 & 7) * 256 + (i3 >> 3)] = v3;
            }
            __syncthreads();
            if (tid < 256) {   // L2: 256 -> 128
                int j = tid & 127, r2 = tid >> 7;
                float acc[4] = {0.f, 0.f, 0.f, 0.f};
                for (int k = 0; k < 256; k++) {
                    float w = w2[(size_t)k * 128 + j];
#pragma unroll
                    for (int q = 0; q < 4; q++) acc[q] += a1s[(r2 * 4 + q) * 256 + k] * w;
                }
                float bb = b2[j];
#pragma unroll
                for (int q = 0; q < 4; q++) a2s[(r2 * 4 + q) * 128 + j] = tanhf_(acc[q] + bb);
            }
            __syncthreads();
            if (tid < 256) {   // L3: 128 -> 64
                int j = tid & 63, r2 = tid >> 6;
                float acc[2] = {0.f, 0.f};
                for (int k = 0; k < 128; k++) {
                    float w = w3[(size_t)k * 64 + j];
#pragma unroll
                    for (int q = 0; q < 2; q++) acc[q] += a2s[(r2 * 2 + q) * 128 + k] * w;
                }
                float bb = b3[j];
#pragma unroll
                for (int q = 0; q < 2; q++) a3s[(r2 * 2 + q) * 64 + j] = tanhf_(acc[q] + bb);
            }
            __syncthreads();
            if (tid < 128) {   // L4: 64 -> 16, write out + pout scratch
                int j = tid & 15, r = tid >> 4;
                float accv = 0.f;
                for (int k = 0; k < 64; k++) accv += a3s[r * 64 + k] * wo[(size_t)k * 16 + j];
                float v = accv + bo[j];
                __hip_atomic_store(&out[(size_t)(m0t + r) * (OUTSTEPS * FEAT) + s * FEAT + j],
                                   v, __ATOMIC_RELAXED, __HIP_MEMORY_SCOPE_AGENT);
                a1s[r * 16 + j] = v;
            }
            __syncthreads();
            if (tid < 64) {    // pack pred -> bf16 x-cols of buffer `par`
                int r = tid >> 3, jp = tid & 7;
                __bf16 lo = (__bf16)a1s[r * 16 + jp * 2];
                __bf16 hi = (__bf16)a1s[r * 16 + jp * 2 + 1];
                unsigned int pv = (unsigned int)(*(unsigned short*)&lo) |
                                  ((unsigned int)(*(unsigned short*)&hi) << 16);
                __bf16* xdst = (par ? Ab1 : Ab0) + (size_t)(m0t + r) * KTOT + jp * 2;
                __hip_atomic_store((unsigned int*)xdst, pv,
                                   __ATOMIC_RELAXED, __HIP_MEMORY_SCOPE_AGENT);
            }
        }
        { unsigned int* cp_ = gctr + (size_t)gi * 16; gi++; BAR_SYNC(cp_, 256u) }

        // AR step
        if (s < OUTSTEPS - 1) {
            const __bf16* bp = par ? ba1 : ba0;
            __bf16* Aw = par ? Ab0 : Ab1;
            const float* tva = out + (size_t)mm * (OUTSTEPS * FEAT) + s * FEAT;
            STEP_CORE(bp, tva, tva, 0)
            if (tid < 256) {
                COPYOUT(Aw)
            }
            par ^= 1;
        }
    }
}

// ---------------------------------------------------------------------------
extern "C" void kernel_launch(void* const* d_in, const int* in_sizes, int n_in,
                              void* d_out, int out_size, void* d_ws, size_t ws_size,
                              hipStream_t stream) {
    (void)in_sizes; (void)n_in; (void)out_size; (void)ws_size;
    const float* x      = (const float*)d_in[0];
    const float* kern   = (const float*)d_in[1];
    const float* rec    = (const float*)d_in[2];
    const float* bias   = (const float*)d_in[3];
    const float* period = (const float*)d_in[4];
    const float* phase  = (const float*)d_in[5];
    const float* ratio  = (const float*)d_in[6];
    const float* w1 = (const float*)d_in[7];
    const float* b1 = (const float*)d_in[8];
    const float* w2 = (const float*)d_in[9];
    const float* b2 = (const float*)d_in[10];
    const float* w3 = (const float*)d_in[11];
    const float* b3 = (const float*)d_in[12];
    const float* wo = (const float*)d_in[13];
    const float* bo = (const float*)d_in[14];
    float* out = (float*)d_out;

    char* ws = (char*)d_ws;
    const size_t WCAT_B = (size_t)NROWS * KTOT * 2;        // 8,912,896
    const size_t AB_B   = (size_t)BATCH * KTOT * 2;        // 557,056
    __bf16* Wcat = (__bf16*)ws;
    __bf16* Ab0  = (__bf16*)(ws + WCAT_B);
    __bf16* Ab1  = (__bf16*)(ws + WCAT_B + AB_B);
    float*  hT   = (float*)(ws + WCAT_B + 2 * AB_B);
    float*  a1T  = hT + (size_t)BATCH * UNITS;
    float*  tvx  = a1T + (size_t)BATCH * 256;
    __bf16* xbf  = (__bf16*)(tvx + (size_t)TSTEPS * BATCH);
    unsigned char* kflag = (unsigned char*)(xbf + (size_t)TSTEPS * BATCH * 16);
    unsigned int*  ctr   = (unsigned int*)(kflag + (size_t)TSTEPS * BATCH);

    (void)hipFuncSetAttribute((const void*)rnn_all,
                              hipFuncAttributeMaxDynamicSharedMemorySize,
                              (int)SMEM_BYTES);

    prep_weights<<<dim3(64, 17), 256, 0, stream>>>(kern, rec, Wcat);
    prep_state<<<512, 256, 0, stream>>>(x, Ab0, Ab1, hT, ctr);
    prep_tv<<<256, 256, 0, stream>>>(x, tvx, kflag, xbf);

    rnn_all<<<dim3(256), dim3(512), SMEM_BYTES, stream>>>(
        Wcat, Ab0, Ab1, hT, a1T, bias, period, phase, ratio,
        tvx, kflag, xbf, w1, b1, w2, b2, w3, b3, wo, bo, out, ctr);
}

// Round 7
// 4297.398 us; speedup vs baseline: 3.2302x; 1.2355x over previous
//
#include <hip/hip_runtime.h>
#include <hip/hip_bf16.h>

#define UNITS 1024
#define FEAT  16
#define TSTEPS 512
#define OUTSTEPS 24
#define BATCH 256
#define KTOT  1088   // 16 (x) + 1024 (h) + 48 pad
#define NROWS 4096   // 4*UNITS, reordered r = 4*u + gate

#define MPB   32     // batch rows per block (m-group width)
#define RPB   128    // weight rows per block (32 units), reg-resident
#define BSB   2320   // Bs LDS row stride in bytes (1160 bf16 cols; %128==16)
#define HST2_OFF 74240           // 32*BSB
#define SMEM_BYTES 83968         // pad to 82KB -> exactly 1 block/CU

#define NGBAR   96
#define CTR_TOT ((TSTEPS * 8 + NGBAR) * 16)

typedef __bf16 bf16x8 __attribute__((ext_vector_type(8)));
typedef float  f32x4  __attribute__((ext_vector_type(4)));

__device__ __forceinline__ float sigmoidf_(float x) { return 1.f / (1.f + __expf(-x)); }
__device__ __forceinline__ float tanhf_(float x)    { return 1.f - 2.f / (__expf(2.f * x) + 1.f); }

// ---------------------------------------------------------------------------
// Build Wcat_T[r][k] (bf16, row-major, stride KTOT), r = 4*u + g.
// ---------------------------------------------------------------------------
__global__ __launch_bounds__(256) void prep_weights(const float* __restrict__ kern,
                                                    const float* __restrict__ rec,
                                                    __bf16* __restrict__ Wcat) {
    __shared__ __align__(16) __bf16 tile[64][72];
    int r0 = blockIdx.x * 64;
    int k0 = blockIdx.y * 64;
    int t  = threadIdx.x;
    int c_off = t & 63;
    int k_grp = t >> 6;
    int g = c_off >> 4, ui = c_off & 15;
    int u0 = r0 >> 2;
    int c  = g * 1024 + u0 + ui;
    int rl = 4 * ui + g;
    for (int i = 0; i < 16; i++) {
        int k = k0 + k_grp * 16 + i;
        float v = 0.f;
        if (k < 16)        v = kern[(size_t)k * NROWS + c];
        else if (k < 1040) v = rec[(size_t)(k - 16) * NROWS + c];
        tile[rl][k_grp * 16 + i] = (__bf16)v;
    }
    __syncthreads();
    int rl2 = t >> 2, ch = t & 3;
    bf16x8* dst = (bf16x8*)(Wcat + (size_t)(r0 + rl2) * KTOT + k0 + ch * 16);
    const bf16x8* src = (const bf16x8*)&tile[rl2][ch * 16];
    dst[0] = src[0];
    dst[1] = src[1];
}

// ---------------------------------------------------------------------------
// Zero hT, zero+x-init Abuf buffers, zero barrier counters.
// ---------------------------------------------------------------------------
__global__ __launch_bounds__(256) void prep_state(const float* __restrict__ x,
                                                  __bf16* __restrict__ Ab0,
                                                  __bf16* __restrict__ Ab1,
                                                  float* __restrict__ hT,
                                                  unsigned int* __restrict__ ctr) {
    int tid = blockIdx.x * 256 + threadIdx.x;
    int np  = gridDim.x * 256;
    for (int i = tid; i < BATCH * UNITS; i += np) hT[i] = 0.f;
    const int AB = BATCH * KTOT;
    for (int i = tid; i < 2 * AB; i += np) {
        int which = (i < AB) ? 0 : 1;
        int p = i - which * AB;
        int col = p % KTOT;
        int m   = p / KTOT;
        __bf16 v = (__bf16)0.f;
        if (which == 0 && col < FEAT) v = (__bf16)x[(size_t)m * TSTEPS * FEAT + col];
        if (which == 0) Ab0[p] = v; else Ab1[p] = v;
    }
    for (int i = tid; i < CTR_TOT; i += np) ctr[i] = 0u;
}

// ---------------------------------------------------------------------------
// Precompute per-(t,m): tv, keep-flag, bf16 x table.
// ---------------------------------------------------------------------------
__global__ __launch_bounds__(256) void prep_tv(const float* __restrict__ x,
                                               float* __restrict__ tvx,
                                               unsigned char* __restrict__ kflag,
                                               __bf16* __restrict__ xbf) {
    int m = blockIdx.x;
    for (int t = threadIdx.x; t < TSTEPS; t += 256) {
        const float* row = x + ((size_t)m * TSTEPS + t) * FEAT;
        f32x4 v0 = *(const f32x4*)row;
        f32x4 v1 = *(const f32x4*)(row + 4);
        f32x4 v2 = *(const f32x4*)(row + 8);
        f32x4 v3 = *(const f32x4*)(row + 12);
        bool keep = true;
#pragma unroll
        for (int i = 0; i < 4; ++i)
            keep = keep && (v0[i] == -1.f) && (v1[i] == -1.f) &&
                   (v2[i] == -1.f) && (v3[i] == -1.f);
        tvx[(size_t)t * BATCH + m]   = v0[0];
        kflag[(size_t)t * BATCH + m] = keep ? 1 : 0;
        __bf16* xo = xbf + ((size_t)t * BATCH + m) * 16;
        bf16x8 o0, o1;
#pragma unroll
        for (int i = 0; i < 4; ++i) { o0[i] = (__bf16)v0[i]; o0[4 + i] = (__bf16)v1[i]; }
#pragma unroll
        for (int i = 0; i < 4; ++i) { o1[i] = (__bf16)v2[i]; o1[4 + i] = (__bf16)v3[i]; }
        *(bf16x8*)xo = o0;
        *(bf16x8*)(xo + 8) = o1;
    }
}

// ---------------------------------------------------------------------------
__device__ __forceinline__ void gate_update(
    float z0, float z1, float z2, float z3,
    float bi, float bf, float bg, float bo,
    float ph, float rp, float ro, float k2,
    float tv, int kf, float& h, float& c) {
    float zi = z0 + bi, zf = z1 + bf, zg = z2 + bg, zo = z3 + bo;
    float ig = sigmoidf_(zi), fg = sigmoidf_(zf), og = sigmoidf_(zo);
    float gv = tanhf_(zg);
    float nc = fg * c + ig * gv;
    float nh = og * tanhf_(nc);
    float cr = (tv - ph) * rp;
    cr = cr - floorf(cr);
    float kup = cr * k2;
    float kk = (cr < ro) ? (2.f - kup) : (0.001f * cr);
    kk = (cr < 0.5f * ro) ? kup : kk;
    float ho = kk * nh + (1.f - kk) * h;
    float co = kk * nc + (1.f - kk) * c;
    if (kf) { ho = h; co = c; }
    h = ho; c = co;
}

// ---------------------------------------------------------------------------
// Mega persistent kernel, v2 tiling:
//   256 blocks = 8 m-groups (mg, 32 batch rows) x 32 r-blocks (rbk, 128
//   weight rows = 32 units). Weights REG-RESIDENT: each of 8 waves holds 16
//   rows x full K in 34 bf16x8 (136 VGPR). Activations (32 m x 1088 k, bf16)
//   staged per step into LDS Bs[32][1160] (sc0 sc1 loads -> regs -> ds_write),
//   shared by all waves. MFMA: D row = weight row -> each lane's f32x4 =
//   i,f,g,o of ONE unit for one m (no cross-wave reduce). Chip-wide MALL
//   traffic 17.8 MB/step (vs 35.6 in v1); group barrier 32 arrivals (vs 64).
// Coherence: R2/R6-proven fence-free protocol (sc1 write-through stores,
// sc0 sc1 loads, relaxed counters, NO cache-maintenance ops).
// ---------------------------------------------------------------------------
#define BAR_SYNC(CP, COUNT) \
    __syncthreads(); \
    if (tid == 0) { \
        __hip_atomic_fetch_add((CP), 1u, __ATOMIC_RELAXED, __HIP_MEMORY_SCOPE_AGENT); \
        while (__hip_atomic_load((CP), __ATOMIC_RELAXED, __HIP_MEMORY_SCOPE_AGENT) < (COUNT)) \
            __builtin_amdgcn_s_sleep(2); \
    } \
    __syncthreads();

#define STEP2(ARP, AWP, TVBLOCK, DO_X) { \
    const char* src_ = (const char*)(ARP) + (size_t)(gm0 + (tid >> 4)) * (KTOT * 2) + (tid & 15) * 16; \
    char* dst_ = bsb + (tid >> 4) * BSB + (tid & 15) * 16; \
    f32x4 s0_; f32x4 s1_; f32x4 s2_; f32x4 s3_; f32x4 s4_; \
    f32x4 s5_; f32x4 s6_; f32x4 s7_; f32x4 s8_; \
    asm volatile( \
        "global_load_dwordx4 %0, %9, off sc0 sc1\n\t" \
        "global_load_dwordx4 %1, %9, off offset:256 sc0 sc1\n\t" \
        "global_load_dwordx4 %2, %9, off offset:512 sc0 sc1\n\t" \
        "global_load_dwordx4 %3, %9, off offset:768 sc0 sc1\n\t" \
        "global_load_dwordx4 %4, %9, off offset:1024 sc0 sc1\n\t" \
        "global_load_dwordx4 %5, %9, off offset:1280 sc0 sc1\n\t" \
        "global_load_dwordx4 %6, %9, off offset:1536 sc0 sc1\n\t" \
        "global_load_dwordx4 %7, %9, off offset:1792 sc0 sc1\n\t" \
        "global_load_dwordx4 %8, %9, off offset:2048 sc0 sc1" \
        : "=&v"(s0_), "=&v"(s1_), "=&v"(s2_), "=&v"(s3_), "=&v"(s4_), \
          "=&v"(s5_), "=&v"(s6_), "=&v"(s7_), "=&v"(s8_) \
        : "v"(src_) : "memory"); \
    float tv0f; float tv1f; int kf0; int kf1; \
    TVBLOCK \
    asm volatile("s_waitcnt vmcnt(0)" ::: "memory"); \
    __builtin_amdgcn_sched_barrier(0); \
    *(f32x4*)(dst_)        = s0_; \
    *(f32x4*)(dst_ + 256)  = s1_; \
    *(f32x4*)(dst_ + 512)  = s2_; \
    *(f32x4*)(dst_ + 768)  = s3_; \
    *(f32x4*)(dst_ + 1024) = s4_; \
    *(f32x4*)(dst_ + 1280) = s5_; \
    *(f32x4*)(dst_ + 1536) = s6_; \
    *(f32x4*)(dst_ + 1792) = s7_; \
    *(f32x4*)(dst_ + 2048) = s8_; \
    __syncthreads(); \
    f32x4 acc0 = {}; f32x4 acc1 = {}; \
    _Pragma("unroll") \
    for (int kt_ = 0; kt_ < 34; ++kt_) { \
        bf16x8 b0_ = *(const bf16x8*)(lbs + kt_ * 64); \
        bf16x8 b1_ = *(const bf16x8*)(lbs2 + kt_ * 64); \
        acc0 = __builtin_amdgcn_mfma_f32_16x16x32_bf16(areg[kt_], b0_, acc0, 0, 0, 0); \
        acc1 = __builtin_amdgcn_mfma_f32_16x16x32_bf16(areg[kt_], b1_, acc1, 0, 0, 0); \
    } \
    gate_update(acc0[0], acc0[1], acc0[2], acc0[3], Bi, Bf, Bg, Bo, Ph, Rp, Ro, K2, tv0f, kf0, h0, c0); \
    *(__bf16*)(hstageb + l16 * 64 + ucol2) = (__bf16)h0; \
    gate_update(acc1[0], acc1[1], acc1[2], acc1[3], Bi, Bf, Bg, Bo, Ph, Rp, Ro, K2, tv1f, kf1, h1, c1); \
    *(__bf16*)(hstageb + (16 + l16) * 64 + ucol2) = (__bf16)h1; \
    __syncthreads(); \
    if (tid < 256) { \
        int rw_ = tid >> 3; int ch_ = tid & 7; \
        unsigned long long v_ = *(const unsigned long long*)(hstageb + rw_ * 64 + ch_ * 8); \
        __hip_atomic_store((unsigned long long*)&(AWP)[(size_t)(gm0 + rw_) * KTOT + 16 + u0 + ch_ * 4], \
                           v_, __ATOMIC_RELAXED, __HIP_MEMORY_SCOPE_AGENT); \
    } \
    DO_X \
}

__global__ __launch_bounds__(512, 2) void rnn_all(
    const __bf16* __restrict__ Wcat,
    __bf16* __restrict__ Ab0, __bf16* __restrict__ Ab1,
    float* __restrict__ hT, float* __restrict__ a1T,
    const float* __restrict__ bias, const float* __restrict__ period,
    const float* __restrict__ phase, const float* __restrict__ ratio,
    const float* __restrict__ tvx, const unsigned char* __restrict__ kflag,
    const __bf16* __restrict__ xbf,
    const float* __restrict__ w1, const float* __restrict__ b1,
    const float* __restrict__ w2, const float* __restrict__ b2,
    const float* __restrict__ w3, const float* __restrict__ b3,
    const float* __restrict__ wo, const float* __restrict__ bo,
    float* __restrict__ out, unsigned int* ctr) {
    extern __shared__ __align__(16) char smem[];
    char*   bsb     = smem;                    // Bs [32][BSB bytes]
    char*   hstageb = smem + HST2_OFF;         // [32 m][64 B = 32 units bf16]
    float*  redf    = (float*)smem;            // dense1 scratch (aliases Bs)

    int b   = blockIdx.x;
    int mg  = b & 7, rbk = b >> 3;
    int tid = threadIdx.x;
    int wave = tid >> 6, lane = tid & 63;
    int l16 = lane & 15, quad = lane >> 4;
    int gm0 = mg * MPB;
    int r0  = rbk * RPB;
    int u0  = rbk * 32;

    // ---- one-time: weights into REGISTERS (16 rows x full K per wave) ----
    bf16x8 areg[34];
    {
        const __bf16* wrow = Wcat + (size_t)(r0 + wave * 16 + l16) * KTOT + quad * 8;
#pragma unroll
        for (int kt = 0; kt < 34; ++kt) areg[kt] = *(const bf16x8*)(wrow + kt * 32);
    }

    // ---- per-lane static params: ONE unit, TWO batch rows ----
    int uu = u0 + wave * 4 + quad;
    int ucol2 = (wave * 4 + quad) * 2;
    float Bi = bias[uu], Bf = bias[UNITS + uu];
    float Bg = bias[2 * UNITS + uu], Bo = bias[3 * UNITS + uu];
    float Ph = phase[uu];
    float Rp = 1.f / period[uu];
    float Ro = ratio[uu], K2 = 2.f / Ro;
    float h0 = 0.f, c0 = 0.f, h1 = 0.f, c1 = 0.f;

    const char* lbs  = bsb + l16 * BSB + quad * 16;
    const char* lbs2 = lbs + 16 * BSB;
    unsigned int* gctr = ctr + TSTEPS * 8 * 16;

    // ---------------- warm phase: 512 steps ----------------
#pragma unroll 1
    for (int t = 0; t < TSTEPS; ++t) {
        const __bf16* Ar = (t & 1) ? Ab1 : Ab0;
        __bf16*       Aw = (t & 1) ? Ab0 : Ab1;
        STEP2(Ar, Aw,
            { tv0f = tvx[(size_t)t * BATCH + gm0 + l16];
              tv1f = tvx[(size_t)t * BATCH + gm0 + 16 + l16];
              kf0  = kflag[(size_t)t * BATCH + gm0 + l16];
              kf1  = kflag[(size_t)t * BATCH + gm0 + 16 + l16]; },
            else if (rbk == 0 && t + 1 < TSTEPS) {
                int i_ = tid - 256; int row_ = i_ >> 3; int ch_ = i_ & 7;
                unsigned v_ = *(const unsigned*)
                    &xbf[((size_t)(t + 1) * BATCH + gm0 + row_) * 16 + ch_ * 2];
                __hip_atomic_store((unsigned*)&Aw[(size_t)(gm0 + row_) * KTOT + ch_ * 2],
                                   v_, __ATOMIC_RELAXED, __HIP_MEMORY_SCOPE_AGENT);
            })
        if (t + 1 < TSTEPS) {
            unsigned int* cp_ = ctr + ((size_t)t * 8 + mg) * 16;
            BAR_SYNC(cp_, 32u)
        }
    }

    // ---------------- AR phase: 24 iterations ----------------
    int gb2 = b & 3, rb2 = b >> 2;     // legacy mapping for dense phases
    int gm2 = gb2 * 64;
    int par = 0;
    int gi = 0;
#pragma unroll 1
    for (int s = 0; s < OUTSTEPS; ++s) {
        // dump h state (fp32, transposed [u][m]) for dense1
        __hip_atomic_store(&hT[(size_t)uu * BATCH + gm0 + l16], h0,
                           __ATOMIC_RELAXED, __HIP_MEMORY_SCOPE_AGENT);
        __hip_atomic_store(&hT[(size_t)uu * BATCH + gm0 + 16 + l16], h1,
                           __ATOMIC_RELAXED, __HIP_MEMORY_SCOPE_AGENT);
        { unsigned int* cp_ = gctr + (size_t)gi * 16; gi++; BAR_SYNC(cp_, 256u) }

        // dense1: a1T[j][m] = tanh(sum_k hT[k][m] * w1[k][j] + b1[j])
        {
            const float* hp0 = hT + (size_t)(wave * 128) * BATCH + gm2 + lane;
            const float* hp1 = hp0 + 4 * BATCH;
            const float* wp0 = w1 + (size_t)(wave * 128) * 256 + rb2 * 4;
            const float* wp1 = wp0 + 4 * 256;
            float d0 = 0.f, d1 = 0.f, d2 = 0.f, d3 = 0.f;
#pragma unroll 1
            for (int it = 0; it < 16; ++it) {
                float x0, x1, x2, x3, x4, x5, x6, x7;
                f32x4 w0_, w1_, w2_, w3_, w4_, w5_, w6_, w7_;
                asm volatile(
                    "global_load_dword %0, %16, off sc0 sc1\n\t"
                    "global_load_dword %1, %16, off offset:1024 sc0 sc1\n\t"
                    "global_load_dword %2, %16, off offset:2048 sc0 sc1\n\t"
                    "global_load_dword %3, %16, off offset:3072 sc0 sc1\n\t"
                    "global_load_dword %4, %17, off sc0 sc1\n\t"
                    "global_load_dword %5, %17, off offset:1024 sc0 sc1\n\t"
                    "global_load_dword %6, %17, off offset:2048 sc0 sc1\n\t"
                    "global_load_dword %7, %17, off offset:3072 sc0 sc1\n\t"
                    "global_load_dwordx4 %8, %18, off\n\t"
                    "global_load_dwordx4 %9, %18, off offset:1024\n\t"
                    "global_load_dwordx4 %10, %18, off offset:2048\n\t"
                    "global_load_dwordx4 %11, %18, off offset:3072\n\t"
                    "global_load_dwordx4 %12, %19, off\n\t"
                    "global_load_dwordx4 %13, %19, off offset:1024\n\t"
                    "global_load_dwordx4 %14, %19, off offset:2048\n\t"
                    "global_load_dwordx4 %15, %19, off offset:3072"
                    : "=&v"(x0), "=&v"(x1), "=&v"(x2), "=&v"(x3),
                      "=&v"(x4), "=&v"(x5), "=&v"(x6), "=&v"(x7),
                      "=&v"(w0_), "=&v"(w1_), "=&v"(w2_), "=&v"(w3_),
                      "=&v"(w4_), "=&v"(w5_), "=&v"(w6_), "=&v"(w7_)
                    : "v"(hp0), "v"(hp1), "v"(wp0), "v"(wp1)
                    : "memory");
                asm volatile("s_waitcnt vmcnt(0)" ::: "memory");
                __builtin_amdgcn_sched_barrier(0);
                d0 += x0 * w0_[0]; d1 += x0 * w0_[1]; d2 += x0 * w0_[2]; d3 += x0 * w0_[3];
                d0 += x1 * w1_[0]; d1 += x1 * w1_[1]; d2 += x1 * w1_[2]; d3 += x1 * w1_[3];
                d0 += x2 * w2_[0]; d1 += x2 * w2_[1]; d2 += x2 * w2_[2]; d3 += x2 * w2_[3];
                d0 += x3 * w3_[0]; d1 += x3 * w3_[1]; d2 += x3 * w3_[2]; d3 += x3 * w3_[3];
                d0 += x4 * w4_[0]; d1 += x4 * w4_[1]; d2 += x4 * w4_[2]; d3 += x4 * w4_[3];
                d0 += x5 * w5_[0]; d1 += x5 * w5_[1]; d2 += x5 * w5_[2]; d3 += x5 * w5_[3];
                d0 += x6 * w6_[0]; d1 += x6 * w6_[1]; d2 += x6 * w6_[2]; d3 += x6 * w6_[3];
                d0 += x7 * w7_[0]; d1 += x7 * w7_[1]; d2 += x7 * w7_[2]; d3 += x7 * w7_[3];
                hp0 += 8 * BATCH; hp1 += 8 * BATCH;
                wp0 += 8 * 256;   wp1 += 8 * 256;
            }
            redf[wave * 256 + 0 * 64 + lane] = d0;
            redf[wave * 256 + 1 * 64 + lane] = d1;
            redf[wave * 256 + 2 * 64 + lane] = d2;
            redf[wave * 256 + 3 * 64 + lane] = d3;
            __syncthreads();
            if (tid < 256) {
                int q = tid >> 6, ml2 = tid & 63;
                float sum = 0.f;
#pragma unroll
                for (int w = 0; w < 8; ++w) sum += redf[w * 256 + q * 64 + ml2];
                sum = tanhf_(sum + b1[rb2 * 4 + q]);
                __hip_atomic_store(&a1T[(size_t)(rb2 * 4 + q) * 256 + gm2 + ml2], sum,
                                   __ATOMIC_RELAXED, __HIP_MEMORY_SCOPE_AGENT);
            }
        }
        { unsigned int* cp_ = gctr + (size_t)gi * 16; gi++; BAR_SYNC(cp_, 256u) }

        // dense tail (blocks rb2<8): L2,L3,L4 for rows m0t..m0t+7
        if (rb2 < 8) {
            int m0t = gm2 + rb2 * 8;
            float* a1s = (float*)smem;        // [8][256]
            float* a2s = a1s + 8 * 256;       // [8][128]
            float* a3s = a2s + 8 * 128;       // [8][64]
            {
                float v0, v1, v2, v3;
                int i0 = tid, i1 = tid + 512, i2 = tid + 1024, i3 = tid + 1536;
                const float* p0 = a1T + (size_t)(i0 >> 3) * 256 + m0t + (i0 & 7);
                const float* p1 = a1T + (size_t)(i1 >> 3) * 256 + m0t + (i1 & 7);
                const float* p2 = a1T + (size_t)(i2 >> 3) * 256 + m0t + (i2 & 7);
                const float* p3 = a1T + (size_t)(i3 >> 3) * 256 + m0t + (i3 & 7);
                asm volatile(
                    "global_load_dword %0, %4, off sc0 sc1\n\t"
                    "global_load_dword %1, %5, off sc0 sc1\n\t"
                    "global_load_dword %2, %6, off sc0 sc1\n\t"
                    "global_load_dword %3, %7, off sc0 sc1"
                    : "=&v"(v0), "=&v"(v1), "=&v"(v2), "=&v"(v3)
                    : "v"(p0), "v"(p1), "v"(p2), "v"(p3) : "memory");
                asm volatile("s_waitcnt vmcnt(0)" ::: "memory");
                __builtin_amdgcn_sched_barrier(0);
                a1s[(i0 & 7) * 256 + (i0 >> 3)] = v0;
                a1s[(i1 & 7) * 256 + (i1 >> 3)] = v1;
                a1s[(i2 & 7) * 256 + (i2 >> 3)] = v2;
                a1s[(i3 & 7) * 256 + (i3 >> 3)] = v3;
            }
            __syncthreads();
            if (tid < 256) {   // L2: 256 -> 128
                int j = tid & 127, r2 = tid >> 7;
                float acc[4] = {0.f, 0.f, 0.f, 0.f};
                for (int k = 0; k < 256; k++) {
                    float w = w2[(size_t)k * 128 + j];
#pragma unroll
                    for (int q = 0; q < 4; q++) acc[q] += a1s[(r2 * 4 + q) * 256 + k] * w;
                }
                float bb = b2[j];
#pragma unroll
                for (int q = 0; q < 4; q++) a2s[(r2 * 4 + q) * 128 + j] = tanhf_(acc[q] + bb);
            }
            __syncthreads();
            if (tid < 256) {   // L3: 128 -> 64
                int j = tid & 63, r2 = tid >> 6;
                float acc[2] = {0.f, 0.f};
                for (int k = 0; k < 128; k++) {
                    float w = w3[(size_t)k * 64 + j];
#pragma unroll
                    for (int q = 0; q < 2; q++) acc[q] += a2s[(r2 * 2 + q) * 128 + k] * w;
                }
                float bb = b3[j];
#pragma unroll
                for (int q = 0; q < 2; q++) a3s[(r2 * 2 + q) * 64 + j] = tanhf_(acc[q] + bb);
            }
            __syncthreads();
            if (tid < 128) {   // L4: 64 -> 16, write out + scratch
                int j = tid & 15, r = tid >> 4;
                float accv = 0.f;
                for (int k = 0; k < 64; k++) accv += a3s[r * 64 + k] * wo[(size_t)k * 16 + j];
                float v = accv + bo[j];
                __hip_atomic_store(&out[(size_t)(m0t + r) * (OUTSTEPS * FEAT) + s * FEAT + j],
                                   v, __ATOMIC_RELAXED, __HIP_MEMORY_SCOPE_AGENT);
                a1s[r * 16 + j] = v;
            }
            __syncthreads();
            if (tid < 64) {    // pack pred -> bf16 x-cols of buffer `par`
                int r = tid >> 3, jp = tid & 7;
                __bf16 lo = (__bf16)a1s[r * 16 + jp * 2];
                __bf16 hi = (__bf16)a1s[r * 16 + jp * 2 + 1];
                unsigned int pv = (unsigned int)(*(unsigned short*)&lo) |
                                  ((unsigned int)(*(unsigned short*)&hi) << 16);
                __bf16* xdst = (par ? Ab1 : Ab0) + (size_t)(m0t + r) * KTOT + jp * 2;
                __hip_atomic_store((unsigned int*)xdst, pv,
                                   __ATOMIC_RELAXED, __HIP_MEMORY_SCOPE_AGENT);
            }
        }
        { unsigned int* cp_ = gctr + (size_t)gi * 16; gi++; BAR_SYNC(cp_, 256u) }

        // AR step
        if (s < OUTSTEPS - 1) {
            const __bf16* Ar = par ? Ab1 : Ab0;
            __bf16*       Aw = par ? Ab0 : Ab1;
            STEP2(Ar, Aw,
                { const float* p0_ = out + (size_t)(gm0 + l16) * (OUTSTEPS * FEAT) + s * FEAT;
                  const float* p1_ = p0_ + (size_t)16 * (OUTSTEPS * FEAT);
                  asm volatile(
                      "global_load_dword %0, %2, off sc0 sc1\n\t"
                      "global_load_dword %1, %3, off sc0 sc1"
                      : "=&v"(tv0f), "=&v"(tv1f) : "v"(p0_), "v"(p1_) : "memory");
                  kf0 = 0; kf1 = 0; },
                )
            par ^= 1;
        }
    }
}

// ---------------------------------------------------------------------------
extern "C" void kernel_launch(void* const* d_in, const int* in_sizes, int n_in,
                              void* d_out, int out_size, void* d_ws, size_t ws_size,
                              hipStream_t stream) {
    (void)in_sizes; (void)n_in; (void)out_size; (void)ws_size;
    const float* x      = (const float*)d_in[0];
    const float* kern   = (const float*)d_in[1];
    const float* rec    = (const float*)d_in[2];
    const float* bias   = (const float*)d_in[3];
    const float* period = (const float*)d_in[4];
    const float* phase  = (const float*)d_in[5];
    const float* ratio  = (const float*)d_in[6];
    const float* w1 = (const float*)d_in[7];
    const float* b1 = (const float*)d_in[8];
    const float* w2 = (const float*)d_in[9];
    const float* b2 = (const float*)d_in[10];
    const float* w3 = (const float*)d_in[11];
    const float* b3 = (const float*)d_in[12];
    const float* wo = (const float*)d_in[13];
    const float* bo = (const float*)d_in[14];
    float* out = (float*)d_out;

    char* ws = (char*)d_ws;
    const size_t WCAT_B = (size_t)NROWS * KTOT * 2;        // 8,912,896
    const size_t AB_B   = (size_t)BATCH * KTOT * 2;        // 557,056
    __bf16* Wcat = (__bf16*)ws;
    __bf16* Ab0  = (__bf16*)(ws + WCAT_B);
    __bf16* Ab1  = (__bf16*)(ws + WCAT_B + AB_B);
    float*  hT   = (float*)(ws + WCAT_B + 2 * AB_B);
    float*  a1T  = hT + (size_t)BATCH * UNITS;
    float*  tvx  = a1T + (size_t)BATCH * 256;
    __bf16* xbf  = (__bf16*)(tvx + (size_t)TSTEPS * BATCH);
    unsigned char* kflag = (unsigned char*)(xbf + (size_t)TSTEPS * BATCH * 16);
    unsigned int*  ctr   = (unsigned int*)(kflag + (size_t)TSTEPS * BATCH);

    (void)hipFuncSetAttribute((const void*)rnn_all,
                              hipFuncAttributeMaxDynamicSharedMemorySize,
                              (int)SMEM_BYTES);

    prep_weights<<<dim3(64, 17), 256, 0, stream>>>(kern, rec, Wcat);
    prep_state<<<512, 256, 0, stream>>>(x, Ab0, Ab1, hT, ctr);
    prep_tv<<<256, 256, 0, stream>>>(x, tvx, kflag, xbf);

    rnn_all<<<dim3(256), dim3(512), SMEM_BYTES, stream>>>(
        Wcat, Ab0, Ab1, hT, a1T, bias, period, phase, ratio,
        tvx, kflag, xbf, w1, b1, w2, b2, w3, b3, wo, bo, out, ctr);
}

// Round 8
// 4149.771 us; speedup vs baseline: 3.3451x; 1.0356x over previous
//
#include <hip/hip_runtime.h>
#include <hip/hip_bf16.h>

#define UNITS 1024
#define FEAT  16
#define TSTEPS 512
#define OUTSTEPS 24
#define BATCH 256
#define KTOT  1088   // 16 (x) + 1024 (h) + 48 pad
#define NROWS 4096   // 4*UNITS, reordered r = 4*u + gate

#define MPB   32     // batch rows per block (m-group width)
#define RPB   128    // weight rows per block (32 units), reg-resident
#define BSB   2320   // Bs LDS row stride in bytes (%128==16)
#define RED2_OFF 74240           // 32*BSB
#define HST2_OFF (RED2_OFF + 16384)
#define SMEM_BYTES (HST2_OFF + 2048)   // 92672 -> 1 block/CU

#define NGBAR   96
#define CTR_TOT ((TSTEPS * 8 + NGBAR) * 16)

typedef __bf16 bf16x8 __attribute__((ext_vector_type(8)));
typedef float  f32x4  __attribute__((ext_vector_type(4)));

__device__ __forceinline__ float sigmoidf_(float x) { return 1.f / (1.f + __expf(-x)); }
__device__ __forceinline__ float tanhf_(float x)    { return 1.f - 2.f / (__expf(2.f * x) + 1.f); }

// ---------------------------------------------------------------------------
// Build Wcat_T[r][k] (bf16, row-major, stride KTOT), r = 4*u + g.
// ---------------------------------------------------------------------------
__global__ __launch_bounds__(256) void prep_weights(const float* __restrict__ kern,
                                                    const float* __restrict__ rec,
                                                    __bf16* __restrict__ Wcat) {
    __shared__ __align__(16) __bf16 tile[64][72];
    int r0 = blockIdx.x * 64;
    int k0 = blockIdx.y * 64;
    int t  = threadIdx.x;
    int c_off = t & 63;
    int k_grp = t >> 6;
    int g = c_off >> 4, ui = c_off & 15;
    int u0 = r0 >> 2;
    int c  = g * 1024 + u0 + ui;
    int rl = 4 * ui + g;
    for (int i = 0; i < 16; i++) {
        int k = k0 + k_grp * 16 + i;
        float v = 0.f;
        if (k < 16)        v = kern[(size_t)k * NROWS + c];
        else if (k < 1040) v = rec[(size_t)(k - 16) * NROWS + c];
        tile[rl][k_grp * 16 + i] = (__bf16)v;
    }
    __syncthreads();
    int rl2 = t >> 2, ch = t & 3;
    bf16x8* dst = (bf16x8*)(Wcat + (size_t)(r0 + rl2) * KTOT + k0 + ch * 16);
    const bf16x8* src = (const bf16x8*)&tile[rl2][ch * 16];
    dst[0] = src[0];
    dst[1] = src[1];
}

// ---------------------------------------------------------------------------
// Zero hT, zero+x-init Abuf buffers, zero barrier counters.
// ---------------------------------------------------------------------------
__global__ __launch_bounds__(256) void prep_state(const float* __restrict__ x,
                                                  __bf16* __restrict__ Ab0,
                                                  __bf16* __restrict__ Ab1,
                                                  float* __restrict__ hT,
                                                  unsigned int* __restrict__ ctr) {
    int tid = blockIdx.x * 256 + threadIdx.x;
    int np  = gridDim.x * 256;
    for (int i = tid; i < BATCH * UNITS; i += np) hT[i] = 0.f;
    const int AB = BATCH * KTOT;
    for (int i = tid; i < 2 * AB; i += np) {
        int which = (i < AB) ? 0 : 1;
        int p = i - which * AB;
        int col = p % KTOT;
        int m   = p / KTOT;
        __bf16 v = (__bf16)0.f;
        if (which == 0 && col < FEAT) v = (__bf16)x[(size_t)m * TSTEPS * FEAT + col];
        if (which == 0) Ab0[p] = v; else Ab1[p] = v;
    }
    for (int i = tid; i < CTR_TOT; i += np) ctr[i] = 0u;
}

// ---------------------------------------------------------------------------
// Precompute per-(t,m): tv, keep-flag, bf16 x table.
// ---------------------------------------------------------------------------
__global__ __launch_bounds__(256) void prep_tv(const float* __restrict__ x,
                                               float* __restrict__ tvx,
                                               unsigned char* __restrict__ kflag,
                                               __bf16* __restrict__ xbf) {
    int m = blockIdx.x;
    for (int t = threadIdx.x; t < TSTEPS; t += 256) {
        const float* row = x + ((size_t)m * TSTEPS + t) * FEAT;
        f32x4 v0 = *(const f32x4*)row;
        f32x4 v1 = *(const f32x4*)(row + 4);
        f32x4 v2 = *(const f32x4*)(row + 8);
        f32x4 v3 = *(const f32x4*)(row + 12);
        bool keep = true;
#pragma unroll
        for (int i = 0; i < 4; ++i)
            keep = keep && (v0[i] == -1.f) && (v1[i] == -1.f) &&
                   (v2[i] == -1.f) && (v3[i] == -1.f);
        tvx[(size_t)t * BATCH + m]   = v0[0];
        kflag[(size_t)t * BATCH + m] = keep ? 1 : 0;
        __bf16* xo = xbf + ((size_t)t * BATCH + m) * 16;
        bf16x8 o0, o1;
#pragma unroll
        for (int i = 0; i < 4; ++i) { o0[i] = (__bf16)v0[i]; o0[4 + i] = (__bf16)v1[i]; }
#pragma unroll
        for (int i = 0; i < 4; ++i) { o1[i] = (__bf16)v2[i]; o1[4 + i] = (__bf16)v3[i]; }
        *(bf16x8*)xo = o0;
        *(bf16x8*)(xo + 8) = o1;
    }
}

// ---------------------------------------------------------------------------
__device__ __forceinline__ void gate_update(
    float z0, float z1, float z2, float z3,
    float bi, float bf, float bg, float bo,
    float ph, float rp, float ro, float k2,
    float tv, int kf, float& h, float& c) {
    float zi = z0 + bi, zf = z1 + bf, zg = z2 + bg, zo = z3 + bo;
    float ig = sigmoidf_(zi), fg = sigmoidf_(zf), og = sigmoidf_(zo);
    float gv = tanhf_(zg);
    float nc = fg * c + ig * gv;
    float nh = og * tanhf_(nc);
    float cr = (tv - ph) * rp;
    cr = cr - floorf(cr);
    float kup = cr * k2;
    float kk = (cr < ro) ? (2.f - kup) : (0.001f * cr);
    kk = (cr < 0.5f * ro) ? kup : kk;
    float ho = kk * nh + (1.f - kk) * h;
    float co = kk * nc + (1.f - kk) * c;
    if (kf) { ho = h; co = c; }
    h = ho; c = co;
}

// ---------------------------------------------------------------------------
// Mega persistent kernel, v3 tiling (kh-split):
//   256 blocks = 8 m-groups x 32 r-blocks (128 weight rows). Waves =
//   (rq 0..3 r-slices of 32 rows) x (kh 0..1 K-halves of 544). Each wave
//   holds 32 rows x 544 K in regs (areg0/areg1[17], 136 VGPR) and issues
//   4 MFMAs per 2 B-reads -> per-CU LDS B-reads HALVED vs v2 (278 KB/step).
//   K-halves exchange partials via redv (16 KB LDS); gate epilogue splits
//   by m-tile (kh0 -> m 0..15, kh1 -> m 16..31), 2 units per lane.
// Coherence: R2/R6-proven fence-free protocol (sc1 write-through stores,
// sc0 sc1 loads, relaxed counters, NO cache-maintenance ops).
// ---------------------------------------------------------------------------
#define BAR_SYNC(CP, COUNT) \
    __syncthreads(); \
    if (tid == 0) { \
        __hip_atomic_fetch_add((CP), 1u, __ATOMIC_RELAXED, __HIP_MEMORY_SCOPE_AGENT); \
        while (__hip_atomic_load((CP), __ATOMIC_RELAXED, __HIP_MEMORY_SCOPE_AGENT) < (COUNT)) \
            __builtin_amdgcn_s_sleep(2); \
    } \
    __syncthreads();

#define STEP2(ARP, AWP, TVBLOCK, DO_X) { \
    const char* src_ = (const char*)(ARP) + (size_t)(gm0 + (tid >> 4)) * (KTOT * 2) + (tid & 15) * 16; \
    char* dst_ = bsb + (tid >> 4) * BSB + (tid & 15) * 16; \
    f32x4 s0_; f32x4 s1_; f32x4 s2_; f32x4 s3_; f32x4 s4_; \
    f32x4 s5_; f32x4 s6_; f32x4 s7_; f32x4 s8_; \
    asm volatile( \
        "global_load_dwordx4 %0, %9, off sc0 sc1\n\t" \
        "global_load_dwordx4 %1, %9, off offset:256 sc0 sc1\n\t" \
        "global_load_dwordx4 %2, %9, off offset:512 sc0 sc1\n\t" \
        "global_load_dwordx4 %3, %9, off offset:768 sc0 sc1\n\t" \
        "global_load_dwordx4 %4, %9, off offset:1024 sc0 sc1\n\t" \
        "global_load_dwordx4 %5, %9, off offset:1280 sc0 sc1\n\t" \
        "global_load_dwordx4 %6, %9, off offset:1536 sc0 sc1\n\t" \
        "global_load_dwordx4 %7, %9, off offset:1792 sc0 sc1\n\t" \
        "global_load_dwordx4 %8, %9, off offset:2048 sc0 sc1" \
        : "=&v"(s0_), "=&v"(s1_), "=&v"(s2_), "=&v"(s3_), "=&v"(s4_), \
          "=&v"(s5_), "=&v"(s6_), "=&v"(s7_), "=&v"(s8_) \
        : "v"(src_) : "memory"); \
    float tv0f; float tv1f; int kf0; int kf1; \
    TVBLOCK \
    asm volatile("s_waitcnt vmcnt(0)" ::: "memory"); \
    __builtin_amdgcn_sched_barrier(0); \
    *(f32x4*)(dst_)        = s0_; \
    *(f32x4*)(dst_ + 256)  = s1_; \
    *(f32x4*)(dst_ + 512)  = s2_; \
    *(f32x4*)(dst_ + 768)  = s3_; \
    *(f32x4*)(dst_ + 1024) = s4_; \
    *(f32x4*)(dst_ + 1280) = s5_; \
    *(f32x4*)(dst_ + 1536) = s6_; \
    *(f32x4*)(dst_ + 1792) = s7_; \
    *(f32x4*)(dst_ + 2048) = s8_; \
    __syncthreads(); \
    f32x4 acc00 = {}; f32x4 acc01 = {}; f32x4 acc10 = {}; f32x4 acc11 = {}; \
    _Pragma("unroll") \
    for (int kt_ = 0; kt_ < 17; ++kt_) { \
        bf16x8 b0_ = *(const bf16x8*)(lbs + kt_ * 64); \
        bf16x8 b1_ = *(const bf16x8*)(lbs2 + kt_ * 64); \
        acc00 = __builtin_amdgcn_mfma_f32_16x16x32_bf16(areg0[kt_], b0_, acc00, 0, 0, 0); \
        acc01 = __builtin_amdgcn_mfma_f32_16x16x32_bf16(areg0[kt_], b1_, acc01, 0, 0, 0); \
        acc10 = __builtin_amdgcn_mfma_f32_16x16x32_bf16(areg1[kt_], b0_, acc10, 0, 0, 0); \
        acc11 = __builtin_amdgcn_mfma_f32_16x16x32_bf16(areg1[kt_], b1_, acc11, 0, 0, 0); \
    } \
    /* park partner's m-tile (mt = kh^1), read own (mt = kh) */ \
    { \
        int po_ = (rq * 4 + (kh ^ 1) * 2) * 64 + lane; \
        redv[po_]      = kh ? acc00 : acc01; \
        redv[po_ + 64] = kh ? acc10 : acc11; \
    } \
    __syncthreads(); \
    { \
        int so_ = (rq * 4 + kh * 2) * 64 + lane; \
        f32x4 zA_ = (kh ? acc01 : acc00) + redv[so_]; \
        f32x4 zB_ = (kh ? acc11 : acc10) + redv[so_ + 64]; \
        float tvf = kh ? tv1f : tv0f; \
        int kf = kh ? kf1 : kf0; \
        gate_update(zA_[0], zA_[1], zA_[2], zA_[3], BiA, BfA, BgA, BoA, \
                    PhA, RpA, RoA, K2A, tvf, kf, hA, cA); \
        *(__bf16*)(hstageb + mloc * 64 + ucolA) = (__bf16)hA; \
        gate_update(zB_[0], zB_[1], zB_[2], zB_[3], BiB, BfB, BgB, BoB, \
                    PhB, RpB, RoB, K2B, tvf, kf, hB, cB); \
        *(__bf16*)(hstageb + mloc * 64 + ucolB) = (__bf16)hB; \
    } \
    __syncthreads(); \
    if (tid < 256) { \
        int rw_ = tid >> 3; int ch_ = tid & 7; \
        unsigned long long v_ = *(const unsigned long long*)(hstageb + rw_ * 64 + ch_ * 8); \
        __hip_atomic_store((unsigned long long*)&(AWP)[(size_t)(gm0 + rw_) * KTOT + 16 + u0 + ch_ * 4], \
                           v_, __ATOMIC_RELAXED, __HIP_MEMORY_SCOPE_AGENT); \
    } \
    DO_X \
}

__global__ __launch_bounds__(512, 2) void rnn_all(
    const __bf16* __restrict__ Wcat,
    __bf16* __restrict__ Ab0, __bf16* __restrict__ Ab1,
    float* __restrict__ hT, float* __restrict__ a1T,
    const float* __restrict__ bias, const float* __restrict__ period,
    const float* __restrict__ phase, const float* __restrict__ ratio,
    const float* __restrict__ tvx, const unsigned char* __restrict__ kflag,
    const __bf16* __restrict__ xbf,
    const float* __restrict__ w1, const float* __restrict__ b1,
    const float* __restrict__ w2, const float* __restrict__ b2,
    const float* __restrict__ w3, const float* __restrict__ b3,
    const float* __restrict__ wo, const float* __restrict__ bo,
    float* __restrict__ out, unsigned int* ctr) {
    extern __shared__ __align__(16) char smem[];
    char*   bsb     = smem;                    // Bs [32][BSB bytes]
    f32x4*  redv    = (f32x4*)(smem + RED2_OFF);  // 16 slots x 64 lanes
    char*   hstageb = smem + HST2_OFF;         // [32 m][64 B = 32 units bf16]
    float*  redf    = (float*)smem;            // dense1 scratch (aliases Bs)

    int b   = blockIdx.x;
    int mg  = b & 7, rbk = b >> 3;
    int tid = threadIdx.x;
    int wave = tid >> 6, lane = tid & 63;
    int rq = wave & 3, kh = wave >> 2;
    int l16 = lane & 15, quad = lane >> 4;
    int gm0 = mg * MPB;
    int r0  = rbk * RPB;
    int u0  = rbk * 32;

    // ---- one-time: weights into REGISTERS (32 rows x K-half per wave) ----
    bf16x8 areg0[17], areg1[17];
    {
        const __bf16* wr0 = Wcat + (size_t)(r0 + rq * 32 + l16) * KTOT + kh * 544 + quad * 8;
        const __bf16* wr1 = wr0 + (size_t)16 * KTOT;
#pragma unroll
        for (int kt = 0; kt < 17; ++kt) {
            areg0[kt] = *(const bf16x8*)(wr0 + kt * 32);
            areg1[kt] = *(const bf16x8*)(wr1 + kt * 32);
        }
    }

    // ---- per-lane static params: TWO units, ONE batch row (m = kh*16+l16) ----
    int uuA = u0 + rq * 8 + quad;
    int uuB = uuA + 4;
    int mloc = kh * 16 + l16;
    int mm = gm0 + mloc;
    int ucolA = (rq * 8 + quad) * 2;
    int ucolB = ucolA + 8;
    float BiA = bias[uuA],             BiB = bias[uuB];
    float BfA = bias[UNITS + uuA],     BfB = bias[UNITS + uuB];
    float BgA = bias[2 * UNITS + uuA], BgB = bias[2 * UNITS + uuB];
    float BoA = bias[3 * UNITS + uuA], BoB = bias[3 * UNITS + uuB];
    float PhA = phase[uuA], PhB = phase[uuB];
    float RpA = 1.f / period[uuA], RpB = 1.f / period[uuB];
    float RoA = ratio[uuA], RoB = ratio[uuB];
    float K2A = 2.f / RoA,  K2B = 2.f / RoB;
    float hA = 0.f, cA = 0.f, hB = 0.f, cB = 0.f;

    const char* lbs  = bsb + l16 * BSB + kh * 1088 + quad * 16;
    const char* lbs2 = lbs + 16 * BSB;
    unsigned int* gctr = ctr + TSTEPS * 8 * 16;

    // ---------------- warm phase: 512 steps ----------------
#pragma unroll 1
    for (int t = 0; t < TSTEPS; ++t) {
        const __bf16* Ar = (t & 1) ? Ab1 : Ab0;
        __bf16*       Aw = (t & 1) ? Ab0 : Ab1;
        STEP2(Ar, Aw,
            { tv0f = tvx[(size_t)t * BATCH + gm0 + l16];
              tv1f = tvx[(size_t)t * BATCH + gm0 + 16 + l16];
              kf0  = kflag[(size_t)t * BATCH + gm0 + l16];
              kf1  = kflag[(size_t)t * BATCH + gm0 + 16 + l16]; },
            else if (rbk == 0 && t + 1 < TSTEPS) {
                int i_ = tid - 256; int row_ = i_ >> 3; int ch_ = i_ & 7;
                unsigned v_ = *(const unsigned*)
                    &xbf[((size_t)(t + 1) * BATCH + gm0 + row_) * 16 + ch_ * 2];
                __hip_atomic_store((unsigned*)&Aw[(size_t)(gm0 + row_) * KTOT + ch_ * 2],
                                   v_, __ATOMIC_RELAXED, __HIP_MEMORY_SCOPE_AGENT);
            })
        if (t + 1 < TSTEPS) {
            unsigned int* cp_ = ctr + ((size_t)t * 8 + mg) * 16;
            BAR_SYNC(cp_, 32u)
        }
    }

    // ---------------- AR phase: 24 iterations ----------------
    int gb2 = b & 3, rb2 = b >> 2;     // legacy mapping for dense phases
    int gm2 = gb2 * 64;
    int par = 0;
    int gi = 0;
#pragma unroll 1
    for (int s = 0; s < OUTSTEPS; ++s) {
        // dump h state (fp32, transposed [u][m]) for dense1
        __hip_atomic_store(&hT[(size_t)uuA * BATCH + mm], hA,
                           __ATOMIC_RELAXED, __HIP_MEMORY_SCOPE_AGENT);
        __hip_atomic_store(&hT[(size_t)uuB * BATCH + mm], hB,
                           __ATOMIC_RELAXED, __HIP_MEMORY_SCOPE_AGENT);
        { unsigned int* cp_ = gctr + (size_t)gi * 16; gi++; BAR_SYNC(cp_, 256u) }

        // dense1: a1T[j][m] = tanh(sum_k hT[k][m] * w1[k][j] + b1[j])
        {
            const float* hp0 = hT + (size_t)(wave * 128) * BATCH + gm2 + lane;
            const float* hp1 = hp0 + 4 * BATCH;
            const float* wp0 = w1 + (size_t)(wave * 128) * 256 + rb2 * 4;
            const float* wp1 = wp0 + 4 * 256;
            float d0 = 0.f, d1 = 0.f, d2 = 0.f, d3 = 0.f;
#pragma unroll 1
            for (int it = 0; it < 16; ++it) {
                float x0, x1, x2, x3, x4, x5, x6, x7;
                f32x4 w0_, w1_, w2_, w3_, w4_, w5_, w6_, w7_;
                asm volatile(
                    "global_load_dword %0, %16, off sc0 sc1\n\t"
                    "global_load_dword %1, %16, off offset:1024 sc0 sc1\n\t"
                    "global_load_dword %2, %16, off offset:2048 sc0 sc1\n\t"
                    "global_load_dword %3, %16, off offset:3072 sc0 sc1\n\t"
                    "global_load_dword %4, %17, off sc0 sc1\n\t"
                    "global_load_dword %5, %17, off offset:1024 sc0 sc1\n\t"
                    "global_load_dword %6, %17, off offset:2048 sc0 sc1\n\t"
                    "global_load_dword %7, %17, off offset:3072 sc0 sc1\n\t"
                    "global_load_dwordx4 %8, %18, off\n\t"
                    "global_load_dwordx4 %9, %18, off offset:1024\n\t"
                    "global_load_dwordx4 %10, %18, off offset:2048\n\t"
                    "global_load_dwordx4 %11, %18, off offset:3072\n\t"
                    "global_load_dwordx4 %12, %19, off\n\t"
                    "global_load_dwordx4 %13, %19, off offset:1024\n\t"
                    "global_load_dwordx4 %14, %19, off offset:2048\n\t"
                    "global_load_dwordx4 %15, %19, off offset:3072"
                    : "=&v"(x0), "=&v"(x1), "=&v"(x2), "=&v"(x3),
                      "=&v"(x4), "=&v"(x5), "=&v"(x6), "=&v"(x7),
                      "=&v"(w0_), "=&v"(w1_), "=&v"(w2_), "=&v"(w3_),
                      "=&v"(w4_), "=&v"(w5_), "=&v"(w6_), "=&v"(w7_)
                    : "v"(hp0), "v"(hp1), "v"(wp0), "v"(wp1)
                    : "memory");
                asm volatile("s_waitcnt vmcnt(0)" ::: "memory");
                __builtin_amdgcn_sched_barrier(0);
                d0 += x0 * w0_[0]; d1 += x0 * w0_[1]; d2 += x0 * w0_[2]; d3 += x0 * w0_[3];
                d0 += x1 * w1_[0]; d1 += x1 * w1_[1]; d2 += x1 * w1_[2]; d3 += x1 * w1_[3];
                d0 += x2 * w2_[0]; d1 += x2 * w2_[1]; d2 += x2 * w2_[2]; d3 += x2 * w2_[3];
                d0 += x3 * w3_[0]; d1 += x3 * w3_[1]; d2 += x3 * w3_[2]; d3 += x3 * w3_[3];
                d0 += x4 * w4_[0]; d1 += x4 * w4_[1]; d2 += x4 * w4_[2]; d3 += x4 * w4_[3];
                d0 += x5 * w5_[0]; d1 += x5 * w5_[1]; d2 += x5 * w5_[2]; d3 += x5 * w5_[3];
                d0 += x6 * w6_[0]; d1 += x6 * w6_[1]; d2 += x6 * w6_[2]; d3 += x6 * w6_[3];
                d0 += x7 * w7_[0]; d1 += x7 * w7_[1]; d2 += x7 * w7_[2]; d3 += x7 * w7_[3];
                hp0 += 8 * BATCH; hp1 += 8 * BATCH;
                wp0 += 8 * 256;   wp1 += 8 * 256;
            }
            redf[wave * 256 + 0 * 64 + lane] = d0;
            redf[wave * 256 + 1 * 64 + lane] = d1;
            redf[wave * 256 + 2 * 64 + lane] = d2;
            redf[wave * 256 + 3 * 64 + lane] = d3;
            __syncthreads();
            if (tid < 256) {
                int q = tid >> 6, ml2 = tid & 63;
                float sum = 0.f;
#pragma unroll
                for (int w = 0; w < 8; ++w) sum += redf[w * 256 + q * 64 + ml2];
                sum = tanhf_(sum + b1[rb2 * 4 + q]);
                __hip_atomic_store(&a1T[(size_t)(rb2 * 4 + q) * 256 + gm2 + ml2], sum,
                                   __ATOMIC_RELAXED, __HIP_MEMORY_SCOPE_AGENT);
            }
        }
        { unsigned int* cp_ = gctr + (size_t)gi * 16; gi++; BAR_SYNC(cp_, 256u) }

        // dense tail (blocks rb2<8): L2,L3,L4 for rows m0t..m0t+7
        if (rb2 < 8) {
            int m0t = gm2 + rb2 * 8;
            float* a1s = (float*)smem;        // [8][256]
            float* a2s = a1s + 8 * 256;       // [8][128]
            float* a3s = a2s + 8 * 128;       // [8][64]
            {
                float v0, v1, v2, v3;
                int i0 = tid, i1 = tid + 512, i2 = tid + 1024, i3 = tid + 1536;
                const float* p0 = a1T + (size_t)(i0 >> 3) * 256 + m0t + (i0 & 7);
                const float* p1 = a1T + (size_t)(i1 >> 3) * 256 + m0t + (i1 & 7);
                const float* p2 = a1T + (size_t)(i2 >> 3) * 256 + m0t + (i2 & 7);
                const float* p3 = a1T + (size_t)(i3 >> 3) * 256 + m0t + (i3 & 7);
                asm volatile(
                    "global_load_dword %0, %4, off sc0 sc1\n\t"
                    "global_load_dword %1, %5, off sc0 sc1\n\t"
                    "global_load_dword %2, %6, off sc0 sc1\n\t"
                    "global_load_dword %3, %7, off sc0 sc1"
                    : "=&v"(v0), "=&v"(v1), "=&v"(v2), "=&v"(v3)
                    : "v"(p0), "v"(p1), "v"(p2), "v"(p3) : "memory");
                asm volatile("s_waitcnt vmcnt(0)" ::: "memory");
                __builtin_amdgcn_sched_barrier(0);
                a1s[(i0 & 7) * 256 + (i0 >> 3)] = v0;
                a1s[(i1 & 7) * 256 + (i1 >> 3)] = v1;
                a1s[(i2 & 7) * 256 + (i2 >> 3)] = v2;
                a1s[(i3 & 7) * 256 + (i3 >> 3)] = v3;
            }
            __syncthreads();
            if (tid < 256) {   // L2: 256 -> 128
                int j = tid & 127, r2 = tid >> 7;
                float acc[4] = {0.f, 0.f, 0.f, 0.f};
                for (int k = 0; k < 256; k++) {
                    float w = w2[(size_t)k * 128 + j];
#pragma unroll
                    for (int q = 0; q < 4; q++) acc[q] += a1s[(r2 * 4 + q) * 256 + k] * w;
                }
                float bb = b2[j];
#pragma unroll
                for (int q = 0; q < 4; q++) a2s[(r2 * 4 + q) * 128 + j] = tanhf_(acc[q] + bb);
            }
            __syncthreads();
            if (tid < 256) {   // L3: 128 -> 64
                int j = tid & 63, r2 = tid >> 6;
                float acc[2] = {0.f, 0.f};
                for (int k = 0; k < 128; k++) {
                    float w = w3[(size_t)k * 64 + j];
#pragma unroll
                    for (int q = 0; q < 2; q++) acc[q] += a2s[(r2 * 2 + q) * 128 + k] * w;
                }
                float bb = b3[j];
#pragma unroll
                for (int q = 0; q < 2; q++) a3s[(r2 * 2 + q) * 64 + j] = tanhf_(acc[q] + bb);
            }
            __syncthreads();
            if (tid < 128) {   // L4: 64 -> 16, write out + scratch
                int j = tid & 15, r = tid >> 4;
                float accv = 0.f;
                for (int k = 0; k < 64; k++) accv += a3s[r * 64 + k] * wo[(size_t)k * 16 + j];
                float v = accv + bo[j];
                __hip_atomic_store(&out[(size_t)(m0t + r) * (OUTSTEPS * FEAT) + s * FEAT + j],
                                   v, __ATOMIC_RELAXED, __HIP_MEMORY_SCOPE_AGENT);
                a1s[r * 16 + j] = v;
            }
            __syncthreads();
            if (tid < 64) {    // pack pred -> bf16 x-cols of buffer `par`
                int r = tid >> 3, jp = tid & 7;
                __bf16 lo = (__bf16)a1s[r * 16 + jp * 2];
                __bf16 hi = (__bf16)a1s[r * 16 + jp * 2 + 1];
                unsigned int pv = (unsigned int)(*(unsigned short*)&lo) |
                                  ((unsigned int)(*(unsigned short*)&hi) << 16);
                __bf16* xdst = (par ? Ab1 : Ab0) + (size_t)(m0t + r) * KTOT + jp * 2;
                __hip_atomic_store((unsigned int*)xdst, pv,
                                   __ATOMIC_RELAXED, __HIP_MEMORY_SCOPE_AGENT);
            }
        }
        { unsigned int* cp_ = gctr + (size_t)gi * 16; gi++; BAR_SYNC(cp_, 256u) }

        // AR step
        if (s < OUTSTEPS - 1) {
            const __bf16* Ar = par ? Ab1 : Ab0;
            __bf16*       Aw = par ? Ab0 : Ab1;
            STEP2(Ar, Aw,
                { const float* p0_ = out + (size_t)(gm0 + l16) * (OUTSTEPS * FEAT) + s * FEAT;
                  const float* p1_ = p0_ + (size_t)16 * (OUTSTEPS * FEAT);
                  asm volatile(
                      "global_load_dword %0, %2, off sc0 sc1\n\t"
                      "global_load_dword %1, %3, off sc0 sc1"
                      : "=&v"(tv0f), "=&v"(tv1f) : "v"(p0_), "v"(p1_) : "memory");
                  kf0 = 0; kf1 = 0; },
                )
            par ^= 1;
        }
    }
}

// ---------------------------------------------------------------------------
extern "C" void kernel_launch(void* const* d_in, const int* in_sizes, int n_in,
                              void* d_out, int out_size, void* d_ws, size_t ws_size,
                              hipStream_t stream) {
    (void)in_sizes; (void)n_in; (void)out_size; (void)ws_size;
    const float* x      = (const float*)d_in[0];
    const float* kern   = (const float*)d_in[1];
    const float* rec    = (const float*)d_in[2];
    const float* bias   = (const float*)d_in[3];
    const float* period = (const float*)d_in[4];
    const float* phase  = (const float*)d_in[5];
    const float* ratio  = (const float*)d_in[6];
    const float* w1 = (const float*)d_in[7];
    const float* b1 = (const float*)d_in[8];
    const float* w2 = (const float*)d_in[9];
    const float* b2 = (const float*)d_in[10];
    const float* w3 = (const float*)d_in[11];
    const float* b3 = (const float*)d_in[12];
    const float* wo = (const float*)d_in[13];
    const float* bo = (const float*)d_in[14];
    float* out = (float*)d_out;

    char* ws = (char*)d_ws;
    const size_t WCAT_B = (size_t)NROWS * KTOT * 2;        // 8,912,896
    const size_t AB_B   = (size_t)BATCH * KTOT * 2;        // 557,056
    __bf16* Wcat = (__bf16*)ws;
    __bf16* Ab0  = (__bf16*)(ws + WCAT_B);
    __bf16* Ab1  = (__bf16*)(ws + WCAT_B + AB_B);
    float*  hT   = (float*)(ws + WCAT_B + 2 * AB_B);
    float*  a1T  = hT + (size_t)BATCH * UNITS;
    float*  tvx  = a1T + (size_t)BATCH * 256;
    __bf16* xbf  = (__bf16*)(tvx + (size_t)TSTEPS * BATCH);
    unsigned char* kflag = (unsigned char*)(xbf + (size_t)TSTEPS * BATCH * 16);
    unsigned int*  ctr   = (unsigned int*)(kflag + (size_t)TSTEPS * BATCH);

    (void)hipFuncSetAttribute((const void*)rnn_all,
                              hipFuncAttributeMaxDynamicSharedMemorySize,
                              (int)SMEM_BYTES);

    prep_weights<<<dim3(64, 17), 256, 0, stream>>>(kern, rec, Wcat);
    prep_state<<<512, 256, 0, stream>>>(x, Ab0, Ab1, hT, ctr);
    prep_tv<<<256, 256, 0, stream>>>(x, tvx, kflag, xbf);

    rnn_all<<<dim3(256), dim3(512), SMEM_BYTES, stream>>>(
        Wcat, Ab0, Ab1, hT, a1T, bias, period, phase, ratio,
        tvx, kflag, xbf, w1, b1, w2, b2, w3, b3, wo, bo, out, ctr);
}

// Round 11
// 4126.912 us; speedup vs baseline: 3.3637x; 1.0055x over previous
//
#include <hip/hip_runtime.h>
#include <hip/hip_bf16.h>

#define UNITS 1024
#define FEAT  16
#define TSTEPS 512
#define OUTSTEPS 24
#define BATCH 256
#define KTOT  1088   // 16 (x) + 1024 (h) + 48 pad
#define NROWS 4096   // 4*UNITS, reordered r = 4*u + gate

#define MPB   32     // batch rows per block (m-group width)
#define RPB   128    // weight rows per block (32 units), reg-resident
#define BSB   2320   // Bs LDS row stride in bytes (%128==16)
#define RED2_OFF 74240           // 32*BSB
#define HST2_OFF (RED2_OFF + 16384)
#define SMEM_BYTES (HST2_OFF + 2048)   // 92672 -> 1 block/CU

#define NGBAR   96
#define WFLAGS  (TSTEPS * 8 * 32)          // per-step warm barrier flags
#define CTR_TOT (WFLAGS + NGBAR * 16)

typedef __bf16 bf16x8 __attribute__((ext_vector_type(8)));
typedef float  f32x4  __attribute__((ext_vector_type(4)));

__device__ __forceinline__ float sigmoidf_(float x) { return 1.f / (1.f + __expf(-x)); }
__device__ __forceinline__ float tanhf_(float x)    { return 1.f - 2.f / (__expf(2.f * x) + 1.f); }

// ---------------------------------------------------------------------------
// Build Wcat_T[r][k] (bf16, row-major, stride KTOT), r = 4*u + g.
// ---------------------------------------------------------------------------
__global__ __launch_bounds__(256) void prep_weights(const float* __restrict__ kern,
                                                    const float* __restrict__ rec,
                                                    __bf16* __restrict__ Wcat) {
    __shared__ __align__(16) __bf16 tile[64][72];
    int r0 = blockIdx.x * 64;
    int k0 = blockIdx.y * 64;
    int t  = threadIdx.x;
    int c_off = t & 63;
    int k_grp = t >> 6;
    int g = c_off >> 4, ui = c_off & 15;
    int u0 = r0 >> 2;
    int c  = g * 1024 + u0 + ui;
    int rl = 4 * ui + g;
    for (int i = 0; i < 16; i++) {
        int k = k0 + k_grp * 16 + i;
        float v = 0.f;
        if (k < 16)        v = kern[(size_t)k * NROWS + c];
        else if (k < 1040) v = rec[(size_t)(k - 16) * NROWS + c];
        tile[rl][k_grp * 16 + i] = (__bf16)v;
    }
    __syncthreads();
    int rl2 = t >> 2, ch = t & 3;
    bf16x8* dst = (bf16x8*)(Wcat + (size_t)(r0 + rl2) * KTOT + k0 + ch * 16);
    const bf16x8* src = (const bf16x8*)&tile[rl2][ch * 16];
    dst[0] = src[0];
    dst[1] = src[1];
}

// ---------------------------------------------------------------------------
// Zero hT, zero+x-init Abuf buffers, zero barrier flags/counters.
// ---------------------------------------------------------------------------
__global__ __launch_bounds__(256) void prep_state(const float* __restrict__ x,
                                                  __bf16* __restrict__ Ab0,
                                                  __bf16* __restrict__ Ab1,
                                                  float* __restrict__ hT,
                                                  unsigned int* __restrict__ ctr) {
    int tid = blockIdx.x * 256 + threadIdx.x;
    int np  = gridDim.x * 256;
    for (int i = tid; i < BATCH * UNITS; i += np) hT[i] = 0.f;
    const int AB = BATCH * KTOT;
    for (int i = tid; i < 2 * AB; i += np) {
        int which = (i < AB) ? 0 : 1;
        int p = i - which * AB;
        int col = p % KTOT;
        int m   = p / KTOT;
        __bf16 v = (__bf16)0.f;
        if (which == 0 && col < FEAT) v = (__bf16)x[(size_t)m * TSTEPS * FEAT + col];
        if (which == 0) Ab0[p] = v; else Ab1[p] = v;
    }
    for (int i = tid; i < CTR_TOT; i += np) ctr[i] = 0u;
}

// ---------------------------------------------------------------------------
// Precompute per-(t,m): tv, keep-flag, bf16 x table.
// ---------------------------------------------------------------------------
__global__ __launch_bounds__(256) void prep_tv(const float* __restrict__ x,
                                               float* __restrict__ tvx,
                                               unsigned char* __restrict__ kflag,
                                               __bf16* __restrict__ xbf) {
    int m = blockIdx.x;
    for (int t = threadIdx.x; t < TSTEPS; t += 256) {
        const float* row = x + ((size_t)m * TSTEPS + t) * FEAT;
        f32x4 v0 = *(const f32x4*)row;
        f32x4 v1 = *(const f32x4*)(row + 4);
        f32x4 v2 = *(const f32x4*)(row + 8);
        f32x4 v3 = *(const f32x4*)(row + 12);
        bool keep = true;
#pragma unroll
        for (int i = 0; i < 4; ++i)
            keep = keep && (v0[i] == -1.f) && (v1[i] == -1.f) &&
                   (v2[i] == -1.f) && (v3[i] == -1.f);
        tvx[(size_t)t * BATCH + m]   = v0[0];
        kflag[(size_t)t * BATCH + m] = keep ? 1 : 0;
        __bf16* xo = xbf + ((size_t)t * BATCH + m) * 16;
        bf16x8 o0, o1;
#pragma unroll
        for (int i = 0; i < 4; ++i) { o0[i] = (__bf16)v0[i]; o0[4 + i] = (__bf16)v1[i]; }
#pragma unroll
        for (int i = 0; i < 4; ++i) { o1[i] = (__bf16)v2[i]; o1[4 + i] = (__bf16)v3[i]; }
        *(bf16x8*)xo = o0;
        *(bf16x8*)(xo + 8) = o1;
    }
}

// ---------------------------------------------------------------------------
__device__ __forceinline__ void gate_update(
    float z0, float z1, float z2, float z3,
    float bi, float bf, float bg, float bo,
    float ph, float rp, float ro, float k2,
    float tv, int kf, float& h, float& c) {
    float zi = z0 + bi, zf = z1 + bf, zg = z2 + bg, zo = z3 + bo;
    float ig = sigmoidf_(zi), fg = sigmoidf_(zf), og = sigmoidf_(zo);
    float gv = tanhf_(zg);
    float nc = fg * c + ig * gv;
    float nh = og * tanhf_(nc);
    float cr = (tv - ph) * rp;
    cr = cr - floorf(cr);
    float kup = cr * k2;
    float kk = (cr < ro) ? (2.f - kup) : (0.001f * cr);
    kk = (cr < 0.5f * ro) ? kup : kk;
    float ho = kk * nh + (1.f - kk) * h;
    float co = kk * nc + (1.f - kk) * c;
    if (kf) { ho = h; co = c; }
    h = ho; c = co;
}

// ---------------------------------------------------------------------------
// Mega persistent kernel, v3 tiling (kh-split) + v4 flag barrier:
//   256 blocks = 8 m-groups x 32 r-blocks (128 weight rows). Waves =
//   (rq 0..3 r-slices of 32 rows) x (kh 0..1 K-halves of 544). Each wave
//   holds 32 rows x 544 K in regs (areg0/areg1[17], 136 VGPR) and issues
//   4 MFMAs per 2 B-reads. K-halves exchange partials via redv (16 KB LDS);
//   gate epilogue splits by m-tile (kh0 -> m 0..15, kh1 -> m 16..31).
//   Warm barrier = per-step FLAGS: 32 parallel sc1 stores (no RMW
//   serialization) + one-wave vectorized sc0sc1 poll with __ballot
//   (no sleep quantization). AR phase keeps counter barriers (72 total).
// Coherence: R2/R6-proven fence-free protocol (sc1 write-through stores,
// sc0 sc1 loads, relaxed counters, NO cache-maintenance ops).
// ---------------------------------------------------------------------------
#define BAR_SYNC(CP, COUNT) \
    __syncthreads(); \
    if (tid == 0) { \
        __hip_atomic_fetch_add((CP), 1u, __ATOMIC_RELAXED, __HIP_MEMORY_SCOPE_AGENT); \
        while (__hip_atomic_load((CP), __ATOMIC_RELAXED, __HIP_MEMORY_SCOPE_AGENT) < (COUNT)) \
            __builtin_amdgcn_s_sleep(2); \
    } \
    __syncthreads();

#define STEP2(ARP, AWP, TVBLOCK, DO_X) { \
    const char* src_ = (const char*)(ARP) + (size_t)(gm0 + (tid >> 4)) * (KTOT * 2) + (tid & 15) * 16; \
    char* dst_ = bsb + (tid >> 4) * BSB + (tid & 15) * 16; \
    f32x4 s0_; f32x4 s1_; f32x4 s2_; f32x4 s3_; f32x4 s4_; \
    f32x4 s5_; f32x4 s6_; f32x4 s7_; f32x4 s8_; \
    asm volatile( \
        "global_load_dwordx4 %0, %9, off sc0 sc1\n\t" \
        "global_load_dwordx4 %1, %9, off offset:256 sc0 sc1\n\t" \
        "global_load_dwordx4 %2, %9, off offset:512 sc0 sc1\n\t" \
        "global_load_dwordx4 %3, %9, off offset:768 sc0 sc1\n\t" \
        "global_load_dwordx4 %4, %9, off offset:1024 sc0 sc1\n\t" \
        "global_load_dwordx4 %5, %9, off offset:1280 sc0 sc1\n\t" \
        "global_load_dwordx4 %6, %9, off offset:1536 sc0 sc1\n\t" \
        "global_load_dwordx4 %7, %9, off offset:1792 sc0 sc1\n\t" \
        "global_load_dwordx4 %8, %9, off offset:2048 sc0 sc1" \
        : "=&v"(s0_), "=&v"(s1_), "=&v"(s2_), "=&v"(s3_), "=&v"(s4_), \
          "=&v"(s5_), "=&v"(s6_), "=&v"(s7_), "=&v"(s8_) \
        : "v"(src_) : "memory"); \
    float tv0f; float tv1f; int kf0; int kf1; \
    TVBLOCK \
    asm volatile("s_waitcnt vmcnt(0)" ::: "memory"); \
    __builtin_amdgcn_sched_barrier(0); \
    *(f32x4*)(dst_)        = s0_; \
    *(f32x4*)(dst_ + 256)  = s1_; \
    *(f32x4*)(dst_ + 512)  = s2_; \
    *(f32x4*)(dst_ + 768)  = s3_; \
    *(f32x4*)(dst_ + 1024) = s4_; \
    *(f32x4*)(dst_ + 1280) = s5_; \
    *(f32x4*)(dst_ + 1536) = s6_; \
    *(f32x4*)(dst_ + 1792) = s7_; \
    *(f32x4*)(dst_ + 2048) = s8_; \
    __syncthreads(); \
    f32x4 acc00 = {}; f32x4 acc01 = {}; f32x4 acc10 = {}; f32x4 acc11 = {}; \
    _Pragma("unroll") \
    for (int kt_ = 0; kt_ < 17; ++kt_) { \
        bf16x8 b0_ = *(const bf16x8*)(lbs + kt_ * 64); \
        bf16x8 b1_ = *(const bf16x8*)(lbs2 + kt_ * 64); \
        acc00 = __builtin_amdgcn_mfma_f32_16x16x32_bf16(areg0[kt_], b0_, acc00, 0, 0, 0); \
        acc01 = __builtin_amdgcn_mfma_f32_16x16x32_bf16(areg0[kt_], b1_, acc01, 0, 0, 0); \
        acc10 = __builtin_amdgcn_mfma_f32_16x16x32_bf16(areg1[kt_], b0_, acc10, 0, 0, 0); \
        acc11 = __builtin_amdgcn_mfma_f32_16x16x32_bf16(areg1[kt_], b1_, acc11, 0, 0, 0); \
    } \
    /* park partner's m-tile (mt = kh^1), read own (mt = kh) */ \
    { \
        int po_ = (rq * 4 + (kh ^ 1) * 2) * 64 + lane; \
        redv[po_]      = kh ? acc00 : acc01; \
        redv[po_ + 64] = kh ? acc10 : acc11; \
    } \
    __syncthreads(); \
    { \
        int so_ = (rq * 4 + kh * 2) * 64 + lane; \
        f32x4 zA_ = (kh ? acc01 : acc00) + redv[so_]; \
        f32x4 zB_ = (kh ? acc11 : acc10) + redv[so_ + 64]; \
        float tvf = kh ? tv1f : tv0f; \
        int kf = kh ? kf1 : kf0; \
        gate_update(zA_[0], zA_[1], zA_[2], zA_[3], BiA, BfA, BgA, BoA, \
                    PhA, RpA, RoA, K2A, tvf, kf, hA, cA); \
        *(__bf16*)(hstageb + mloc * 64 + ucolA) = (__bf16)hA; \
        gate_update(zB_[0], zB_[1], zB_[2], zB_[3], BiB, BfB, BgB, BoB, \
                    PhB, RpB, RoB, K2B, tvf, kf, hB, cB); \
        *(__bf16*)(hstageb + mloc * 64 + ucolB) = (__bf16)hB; \
    } \
    __syncthreads(); \
    if (tid < 256) { \
        int rw_ = tid >> 3; int ch_ = tid & 7; \
        unsigned long long v_ = *(const unsigned long long*)(hstageb + rw_ * 64 + ch_ * 8); \
        __hip_atomic_store((unsigned long long*)&(AWP)[(size_t)(gm0 + rw_) * KTOT + 16 + u0 + ch_ * 4], \
                           v_, __ATOMIC_RELAXED, __HIP_MEMORY_SCOPE_AGENT); \
    } \
    DO_X \
}

__global__ __launch_bounds__(512, 2) void rnn_all(
    const __bf16* __restrict__ Wcat,
    __bf16* __restrict__ Ab0, __bf16* __restrict__ Ab1,
    float* __restrict__ hT, float* __restrict__ a1T,
    const float* __restrict__ bias, const float* __restrict__ period,
    const float* __restrict__ phase, const float* __restrict__ ratio,
    const float* __restrict__ tvx, const unsigned char* __restrict__ kflag,
    const __bf16* __restrict__ xbf,
    const float* __restrict__ w1, const float* __restrict__ b1,
    const float* __restrict__ w2, const float* __restrict__ b2,
    const float* __restrict__ w3, const float* __restrict__ b3,
    const float* __restrict__ wo, const float* __restrict__ bo,
    float* __restrict__ out, unsigned int* ctr) {
    extern __shared__ __align__(16) char smem[];
    char*   bsb     = smem;                    // Bs [32][BSB bytes]
    f32x4*  redv    = (f32x4*)(smem + RED2_OFF);  // 16 slots x 64 lanes
    char*   hstageb = smem + HST2_OFF;         // [32 m][64 B = 32 units bf16]
    float*  redf    = (float*)smem;            // dense1 scratch (aliases Bs)

    int b   = blockIdx.x;
    int mg  = b & 7, rbk = b >> 3;
    int tid = threadIdx.x;
    int wave = tid >> 6, lane = tid & 63;
    int rq = wave & 3, kh = wave >> 2;
    int l16 = lane & 15, quad = lane >> 4;
    int gm0 = mg * MPB;
    int r0  = rbk * RPB;
    int u0  = rbk * 32;

    // ---- one-time: weights into REGISTERS (32 rows x K-half per wave) ----
    bf16x8 areg0[17], areg1[17];
    {
        const __bf16* wr0 = Wcat + (size_t)(r0 + rq * 32 + l16) * KTOT + kh * 544 + quad * 8;
        const __bf16* wr1 = wr0 + (size_t)16 * KTOT;
#pragma unroll
        for (int kt = 0; kt < 17; ++kt) {
            areg0[kt] = *(const bf16x8*)(wr0 + kt * 32);
            areg1[kt] = *(const bf16x8*)(wr1 + kt * 32);
        }
    }

    // ---- per-lane static params: TWO units, ONE batch row (m = kh*16+l16) ----
    int uuA = u0 + rq * 8 + quad;
    int uuB = uuA + 4;
    int mloc = kh * 16 + l16;
    int mm = gm0 + mloc;
    int ucolA = (rq * 8 + quad) * 2;
    int ucolB = ucolA + 8;
    float BiA = bias[uuA],             BiB = bias[uuB];
    float BfA = bias[UNITS + uuA],     BfB = bias[UNITS + uuB];
    float BgA = bias[2 * UNITS + uuA], BgB = bias[2 * UNITS + uuB];
    float BoA = bias[3 * UNITS + uuA], BoB = bias[3 * UNITS + uuB];
    float PhA = phase[uuA], PhB = phase[uuB];
    float RpA = 1.f / period[uuA], RpB = 1.f / period[uuB];
    float RoA = ratio[uuA], RoB = ratio[uuB];
    float K2A = 2.f / RoA,  K2B = 2.f / RoB;
    float hA = 0.f, cA = 0.f, hB = 0.f, cB = 0.f;

    const char* lbs  = bsb + l16 * BSB + kh * 1088 + quad * 16;
    const char* lbs2 = lbs + 16 * BSB;
    unsigned int* gctr = ctr + WFLAGS;

    // ---------------- warm phase: 512 steps ----------------
#pragma unroll 1
    for (int t = 0; t < TSTEPS; ++t) {
        const __bf16* Ar = (t & 1) ? Ab1 : Ab0;
        __bf16*       Aw = (t & 1) ? Ab0 : Ab1;
        STEP2(Ar, Aw,
            { tv0f = tvx[(size_t)t * BATCH + gm0 + l16];
              tv1f = tvx[(size_t)t * BATCH + gm0 + 16 + l16];
              kf0  = kflag[(size_t)t * BATCH + gm0 + l16];
              kf1  = kflag[(size_t)t * BATCH + gm0 + 16 + l16]; },
            else if (rbk == 0 && t + 1 < TSTEPS) {
                int i_ = tid - 256; int row_ = i_ >> 3; int ch_ = i_ & 7;
                unsigned v_ = *(const unsigned*)
                    &xbf[((size_t)(t + 1) * BATCH + gm0 + row_) * 16 + ch_ * 2];
                __hip_atomic_store((unsigned*)&Aw[(size_t)(gm0 + row_) * KTOT + ch_ * 2],
                                   v_, __ATOMIC_RELAXED, __HIP_MEMORY_SCOPE_AGENT);
            })
        if (t + 1 < TSTEPS) {
            // flag barrier: 32 parallel arrival stores + one-wave vector poll
            __syncthreads();   // drains h/x stores (vmcnt 0) before flag
            if (tid == 0)
                __hip_atomic_store(ctr + ((size_t)t * 8 + mg) * 32 + rbk, 1u,
                                   __ATOMIC_RELAXED, __HIP_MEMORY_SCOPE_AGENT);
            if (tid < 64) {
                const unsigned int* fp = ctr + ((size_t)t * 8 + mg) * 32 + (lane & 31);
                while (1) {
                    unsigned int v;
                    asm volatile("global_load_dword %0, %1, off sc0 sc1\n\t"
                                 "s_waitcnt vmcnt(0)"
                                 : "=v"(v) : "v"(fp) : "memory");
                    if (__ballot(lane >= 32 || v != 0) == ~0ull) break;
                    __builtin_amdgcn_s_sleep(1);
                }
            }
            __syncthreads();
        }
    }

    // ---------------- AR phase: 24 iterations ----------------
    int gb2 = b & 3, rb2 = b >> 2;     // legacy mapping for dense phases
    int gm2 = gb2 * 64;
    int par = 0;
    int gi = 0;
#pragma unroll 1
    for (int s = 0; s < OUTSTEPS; ++s) {
        // dump h state (fp32, transposed [u][m]) for dense1
        __hip_atomic_store(&hT[(size_t)uuA * BATCH + mm], hA,
                           __ATOMIC_RELAXED, __HIP_MEMORY_SCOPE_AGENT);
        __hip_atomic_store(&hT[(size_t)uuB * BATCH + mm], hB,
                           __ATOMIC_RELAXED, __HIP_MEMORY_SCOPE_AGENT);
        { unsigned int* cp_ = gctr + (size_t)gi * 16; gi++; BAR_SYNC(cp_, 256u) }

        // dense1: a1T[j][m] = tanh(sum_k hT[k][m] * w1[k][j] + b1[j])
        {
            const float* hp0 = hT + (size_t)(wave * 128) * BATCH + gm2 + lane;
            const float* hp1 = hp0 + 4 * BATCH;
            const float* wp0 = w1 + (size_t)(wave * 128) * 256 + rb2 * 4;
            const float* wp1 = wp0 + 4 * 256;
            float d0 = 0.f, d1 = 0.f, d2 = 0.f, d3 = 0.f;
#pragma unroll 1
            for (int it = 0; it < 16; ++it) {
                float x0, x1, x2, x3, x4, x5, x6, x7;
                f32x4 w0_, w1_, w2_, w3_, w4_, w5_, w6_, w7_;
                asm volatile(
                    "global_load_dword %0, %16, off sc0 sc1\n\t"
                    "global_load_dword %1, %16, off offset:1024 sc0 sc1\n\t"
                    "global_load_dword %2, %16, off offset:2048 sc0 sc1\n\t"
                    "global_load_dword %3, %16, off offset:3072 sc0 sc1\n\t"
                    "global_load_dword %4, %17, off sc0 sc1\n\t"
                    "global_load_dword %5, %17, off offset:1024 sc0 sc1\n\t"
                    "global_load_dword %6, %17, off offset:2048 sc0 sc1\n\t"
                    "global_load_dword %7, %17, off offset:3072 sc0 sc1\n\t"
                    "global_load_dwordx4 %8, %18, off\n\t"
                    "global_load_dwordx4 %9, %18, off offset:1024\n\t"
                    "global_load_dwordx4 %10, %18, off offset:2048\n\t"
                    "global_load_dwordx4 %11, %18, off offset:3072\n\t"
                    "global_load_dwordx4 %12, %19, off\n\t"
                    "global_load_dwordx4 %13, %19, off offset:1024\n\t"
                    "global_load_dwordx4 %14, %19, off offset:2048\n\t"
                    "global_load_dwordx4 %15, %19, off offset:3072"
                    : "=&v"(x0), "=&v"(x1), "=&v"(x2), "=&v"(x3),
                      "=&v"(x4), "=&v"(x5), "=&v"(x6), "=&v"(x7),
                      "=&v"(w0_), "=&v"(w1_), "=&v"(w2_), "=&v"(w3_),
                      "=&v"(w4_), "=&v"(w5_), "=&v"(w6_), "=&v"(w7_)
                    : "v"(hp0), "v"(hp1), "v"(wp0), "v"(wp1)
                    : "memory");
                asm volatile("s_waitcnt vmcnt(0)" ::: "memory");
                __builtin_amdgcn_sched_barrier(0);
                d0 += x0 * w0_[0]; d1 += x0 * w0_[1]; d2 += x0 * w0_[2]; d3 += x0 * w0_[3];
                d0 += x1 * w1_[0]; d1 += x1 * w1_[1]; d2 += x1 * w1_[2]; d3 += x1 * w1_[3];
                d0 += x2 * w2_[0]; d1 += x2 * w2_[1]; d2 += x2 * w2_[2]; d3 += x2 * w2_[3];
                d0 += x3 * w3_[0]; d1 += x3 * w3_[1]; d2 += x3 * w3_[2]; d3 += x3 * w3_[3];
                d0 += x4 * w4_[0]; d1 += x4 * w4_[1]; d2 += x4 * w4_[2]; d3 += x4 * w4_[3];
                d0 += x5 * w5_[0]; d1 += x5 * w5_[1]; d2 += x5 * w5_[2]; d3 += x5 * w5_[3];
                d0 += x6 * w6_[0]; d1 += x6 * w6_[1]; d2 += x6 * w6_[2]; d3 += x6 * w6_[3];
                d0 += x7 * w7_[0]; d1 += x7 * w7_[1]; d2 += x7 * w7_[2]; d3 += x7 * w7_[3];
                hp0 += 8 * BATCH; hp1 += 8 * BATCH;
                wp0 += 8 * 256;   wp1 += 8 * 256;
            }
            redf[wave * 256 + 0 * 64 + lane] = d0;
            redf[wave * 256 + 1 * 64 + lane] = d1;
            redf[wave * 256 + 2 * 64 + lane] = d2;
            redf[wave * 256 + 3 * 64 + lane] = d3;
            __syncthreads();
            if (tid < 256) {
                int q = tid >> 6, ml2 = tid & 63;
                float sum = 0.f;
#pragma unroll
                for (int w = 0; w < 8; ++w) sum += redf[w * 256 + q * 64 + ml2];
                sum = tanhf_(sum + b1[rb2 * 4 + q]);
                __hip_atomic_store(&a1T[(size_t)(rb2 * 4 + q) * 256 + gm2 + ml2], sum,
                                   __ATOMIC_RELAXED, __HIP_MEMORY_SCOPE_AGENT);
            }
        }
        { unsigned int* cp_ = gctr + (size_t)gi * 16; gi++; BAR_SYNC(cp_, 256u) }

        // dense tail (blocks rb2<8): L2,L3,L4 for rows m0t..m0t+7
        if (rb2 < 8) {
            int m0t = gm2 + rb2 * 8;
            float* a1s = (float*)smem;        // [8][256]
            float* a2s = a1s + 8 * 256;       // [8][128]
            float* a3s = a2s + 8 * 128;       // [8][64]
            {
                float v0, v1, v2, v3;
                int i0 = tid, i1 = tid + 512, i2 = tid + 1024, i3 = tid + 1536;
                const float* p0 = a1T + (size_t)(i0 >> 3) * 256 + m0t + (i0 & 7);
                const float* p1 = a1T + (size_t)(i1 >> 3) * 256 + m0t + (i1 & 7);
                const float* p2 = a1T + (size_t)(i2 >> 3) * 256 + m0t + (i2 & 7);
                const float* p3 = a1T + (size_t)(i3 >> 3) * 256 + m0t + (i3 & 7);
                asm volatile(
                    "global_load_dword %0, %4, off sc0 sc1\n\t"
                    "global_load_dword %1, %5, off sc0 sc1\n\t"
                    "global_load_dword %2, %6, off sc0 sc1\n\t"
                    "global_load_dword %3, %7, off sc0 sc1"
                    : "=&v"(v0), "=&v"(v1), "=&v"(v2), "=&v"(v3)
                    : "v"(p0), "v"(p1), "v"(p2), "v"(p3) : "memory");
                asm volatile("s_waitcnt vmcnt(0)" ::: "memory");
                __builtin_amdgcn_sched_barrier(0);
                a1s[(i0 & 7) * 256 + (i0 >> 3)] = v0;
                a1s[(i1 & 7) * 256 + (i1 >> 3)] = v1;
                a1s[(i2 & 7) * 256 + (i2 >> 3)] = v2;
                a1s[(i3 & 7) * 256 + (i3 >> 3)] = v3;
            }
            __syncthreads();
            if (tid < 256) {   // L2: 256 -> 128
                int j = tid & 127, r2 = tid >> 7;
                float acc[4] = {0.f, 0.f, 0.f, 0.f};
                for (int k = 0; k < 256; k++) {
                    float w = w2[(size_t)k * 128 + j];
#pragma unroll
                    for (int q = 0; q < 4; q++) acc[q] += a1s[(r2 * 4 + q) * 256 + k] * w;
                }
                float bb = b2[j];
#pragma unroll
                for (int q = 0; q < 4; q++) a2s[(r2 * 4 + q) * 128 + j] = tanhf_(acc[q] + bb);
            }
            __syncthreads();
            if (tid < 256) {   // L3: 128 -> 64
                int j = tid & 63, r2 = tid >> 6;
                float acc[2] = {0.f, 0.f};
                for (int k = 0; k < 128; k++) {
                    float w = w3[(size_t)k * 64 + j];
#pragma unroll
                    for (int q = 0; q < 2; q++) acc[q] += a2s[(r2 * 2 + q) * 128 + k] * w;
                }
                float bb = b3[j];
#pragma unroll
                for (int q = 0; q < 2; q++) a3s[(r2 * 2 + q) * 64 + j] = tanhf_(acc[q] + bb);
            }
            __syncthreads();
            if (tid < 128) {   // L4: 64 -> 16, write out + scratch
                int j = tid & 15, r = tid >> 4;
                float accv = 0.f;
                for (int k = 0; k < 64; k++) accv += a3s[r * 64 + k] * wo[(size_t)k * 16 + j];
                float v = accv + bo[j];
                __hip_atomic_store(&out[(size_t)(m0t + r) * (OUTSTEPS * FEAT) + s * FEAT + j],
                                   v, __ATOMIC_RELAXED, __HIP_MEMORY_SCOPE_AGENT);
                a1s[r * 16 + j] = v;
            }
            __syncthreads();
            if (tid < 64) {    // pack pred -> bf16 x-cols of buffer `par`
                int r = tid >> 3, jp = tid & 7;
                __bf16 lo = (__bf16)a1s[r * 16 + jp * 2];
                __bf16 hi = (__bf16)a1s[r * 16 + jp * 2 + 1];
                unsigned int pv = (unsigned int)(*(unsigned short*)&lo) |
                                  ((unsigned int)(*(unsigned short*)&hi) << 16);
                __bf16* xdst = (par ? Ab1 : Ab0) + (size_t)(m0t + r) * KTOT + jp * 2;
                __hip_atomic_store((unsigned int*)xdst, pv,
                                   __ATOMIC_RELAXED, __HIP_MEMORY_SCOPE_AGENT);
            }
        }
        { unsigned int* cp_ = gctr + (size_t)gi * 16; gi++; BAR_SYNC(cp_, 256u) }

        // AR step
        if (s < OUTSTEPS - 1) {
            const __bf16* Ar = par ? Ab1 : Ab0;
            __bf16*       Aw = par ? Ab0 : Ab1;
            STEP2(Ar, Aw,
                { const float* p0_ = out + (size_t)(gm0 + l16) * (OUTSTEPS * FEAT) + s * FEAT;
                  const float* p1_ = p0_ + (size_t)16 * (OUTSTEPS * FEAT);
                  asm volatile(
                      "global_load_dword %0, %2, off sc0 sc1\n\t"
                      "global_load_dword %1, %3, off sc0 sc1"
                      : "=&v"(tv0f), "=&v"(tv1f) : "v"(p0_), "v"(p1_) : "memory");
                  kf0 = 0; kf1 = 0; },
                )
            par ^= 1;
        }
    }
}

// ---------------------------------------------------------------------------
extern "C" void kernel_launch(void* const* d_in, const int* in_sizes, int n_in,
                              void* d_out, int out_size, void* d_ws, size_t ws_size,
                              hipStream_t stream) {
    (void)in_sizes; (void)n_in; (void)out_size; (void)ws_size;
    const float* x      = (const float*)d_in[0];
    const float* kern   = (const float*)d_in[1];
    const float* rec    = (const float*)d_in[2];
    const float* bias   = (const float*)d_in[3];
    const float* period = (const float*)d_in[4];
    const float* phase  = (const float*)d_in[5];
    const float* ratio  = (const float*)d_in[6];
    const float* w1 = (const float*)d_in[7];
    const float* b1 = (const float*)d_in[8];
    const float* w2 = (const float*)d_in[9];
    const float* b2 = (const float*)d_in[10];
    const float* w3 = (const float*)d_in[11];
    const float* b3 = (const float*)d_in[12];
    const float* wo = (const float*)d_in[13];
    const float* bo = (const float*)d_in[14];
    float* out = (float*)d_out;

    char* ws = (char*)d_ws;
    const size_t WCAT_B = (size_t)NROWS * KTOT * 2;        // 8,912,896
    const size_t AB_B   = (size_t)BATCH * KTOT * 2;        // 557,056
    __bf16* Wcat = (__bf16*)ws;
    __bf16* Ab0  = (__bf16*)(ws + WCAT_B);
    __bf16* Ab1  = (__bf16*)(ws + WCAT_B + AB_B);
    float*  hT   = (float*)(ws + WCAT_B + 2 * AB_B);
    float*  a1T  = hT + (size_t)BATCH * UNITS;
    float*  tvx  = a1T + (size_t)BATCH * 256;
    __bf16* xbf  = (__bf16*)(tvx + (size_t)TSTEPS * BATCH);
    unsigned char* kflag = (unsigned char*)(xbf + (size_t)TSTEPS * BATCH * 16);
    unsigned int*  ctr   = (unsigned int*)(kflag + (size_t)TSTEPS * BATCH);

    (void)hipFuncSetAttribute((const void*)rnn_all,
                              hipFuncAttributeMaxDynamicSharedMemorySize,
                              (int)SMEM_BYTES);

    prep_weights<<<dim3(64, 17), 256, 0, stream>>>(kern, rec, Wcat);
    prep_state<<<512, 256, 0, stream>>>(x, Ab0, Ab1, hT, ctr);
    prep_tv<<<256, 256, 0, stream>>>(x, tvx, kflag, xbf);

    rnn_all<<<dim3(256), dim3(512), SMEM_BYTES, stream>>>(
        Wcat, Ab0, Ab1, hT, a1T, bias, period, phase, ratio,
        tvx, kflag, xbf, w1, b1, w2, b2, w3, b3, wo, bo, out, ctr);
}